// Round 4
// baseline (1103.619 us; speedup 1.0000x reference)
//
#include <hip/hip_runtime.h>
#include <cstdint>
#include <cstddef>

typedef __attribute__((ext_vector_type(8))) short short8;
typedef __attribute__((ext_vector_type(4))) float f32x4;
typedef unsigned short u16;
typedef unsigned int u32;
typedef unsigned long long u64;

__device__ __forceinline__ u16 f2bf(float f) {
    u32 u = __float_as_uint(f);
    u = (u + 0x7FFFu + ((u >> 16) & 1u)) >> 16;
    return (u16)u;
}

// ---------------------------------------------------------------------------
// Elementwise cast fp32 -> bf16 (vectorized x4). n must be multiple of 4.
__global__ void cast_bf16_kernel(const float* __restrict__ src, u16* __restrict__ dst) {
    int i = blockIdx.x * 256 + threadIdx.x;
    float4 v = *((const float4*)src + i);
    ushort4 r;
    r.x = f2bf(v.x); r.y = f2bf(v.y); r.z = f2bf(v.z); r.w = f2bf(v.w);
    *((ushort4*)dst + i) = r;
}

// ---------------------------------------------------------------------------
// Tiled transpose: src fp32 [R][C] -> dst bf16 [C][R]. grid=(C/32, R/32), block=256.
__global__ void cast_transpose_kernel(const float* __restrict__ src, u16* __restrict__ dst,
                                      int R, int C) {
    __shared__ float tile[32][33];
    int tx = threadIdx.x & 31, ty = threadIdx.x >> 5;
    int c0 = blockIdx.x * 32, r0 = blockIdx.y * 32;
#pragma unroll
    for (int j = 0; j < 4; j++)
        tile[ty + 8 * j][tx] = src[(size_t)(r0 + ty + 8 * j) * C + c0 + tx];
    __syncthreads();
#pragma unroll
    for (int j = 0; j < 4; j++)
        dst[(size_t)(c0 + ty + 8 * j) * R + r0 + tx] = f2bf(tile[tx][ty + 8 * j]);
}

// Tiled transpose: src fp32 [R][C] -> dst fp32 [C][R].
__global__ void transpose_f32_kernel(const float* __restrict__ src, float* __restrict__ dst,
                                     int R, int C) {
    __shared__ float tile[32][33];
    int tx = threadIdx.x & 31, ty = threadIdx.x >> 5;
    int c0 = blockIdx.x * 32, r0 = blockIdx.y * 32;
#pragma unroll
    for (int j = 0; j < 4; j++)
        tile[ty + 8 * j][tx] = src[(size_t)(r0 + ty + 8 * j) * C + c0 + tx];
    __syncthreads();
#pragma unroll
    for (int j = 0; j < 4; j++)
        dst[(size_t)(c0 + ty + 8 * j) * R + r0 + tx] = tile[tx][ty + 8 * j];
}

// ---------------------------------------------------------------------------
// mem_keys -> mn (fp32 row-normalized, for argmax) and Kb (bf16 raw, for attention)
__global__ __launch_bounds__(256) void key_prep_kernel(const float* __restrict__ mk,
                                                       float* __restrict__ mn,
                                                       u16* __restrict__ Kb) {
    int row = blockIdx.x, tid = threadIdx.x;
    const float* src = mk + (size_t)row * 512;
    float x0 = src[tid], x1 = src[tid + 256];
    float ss = x0 * x0 + x1 * x1;
#pragma unroll
    for (int m = 1; m < 64; m <<= 1) ss += __shfl_xor(ss, m);
    __shared__ float sred[4];
    if ((tid & 63) == 0) sred[tid >> 6] = ss;
    __syncthreads();
    float tot = sred[0] + sred[1] + sred[2] + sred[3];
    float inv = 1.0f / fmaxf(sqrtf(tot), 1e-8f);
    mn[(size_t)row * 512 + tid] = x0 * inv;
    mn[(size_t)row * 512 + tid + 256] = x1 * inv;
    Kb[(size_t)row * 512 + tid] = f2bf(x0);
    Kb[(size_t)row * 512 + tid + 256] = f2bf(x1);
}

// ---------------------------------------------------------------------------
// GEMM: C[M,N] = A[M,K] * Bt[N,K]^T + bias[N].  bf16 inputs, fp32 accumulate.
// BM=128 fixed, BN template (128 or 64). block=256 (4 waves, 2x2 quadrants).
// EPI==0: write fp32 C row-major [M,N].
// EPI==1: q-proj permute: row=(b*1024+n), col=(h*512+d) -> Qatt bf16 [((b*8+h)*1024+n)*512+d]
template <int BN, int EPI>
__global__ __launch_bounds__(256, 2) void gemm_bt_kernel(const u16* __restrict__ A,
                                                         const u16* __restrict__ Bt,
                                                         const float* __restrict__ bias,
                                                         void* __restrict__ Cout,
                                                         int M, int N, int K) {
    constexpr int NT = BN / 32;
    __shared__ __align__(16) u16 A_lds[128 * 40];
    __shared__ __align__(16) u16 B_lds[BN * 40];
    int tid = threadIdx.x;
    int w = tid >> 6, lane = tid & 63, l15 = lane & 15, quad = lane >> 4;
    int wm = w >> 1, wn = w & 1;
    int n0 = blockIdx.x * BN, m0 = blockIdx.y * 128;

    f32x4 acc[4][NT];
#pragma unroll
    for (int i = 0; i < 4; i++)
#pragma unroll
        for (int j = 0; j < NT; j++) acc[i][j] = (f32x4)(0.0f);

    for (int kt = 0; kt < K; kt += 32) {
        __syncthreads();
#pragma unroll
        for (int i = 0; i < 2; i++) {
            int c = i * 256 + tid;
            int r = c >> 2, col = c & 3;
            *(uint4*)&A_lds[r * 40 + col * 8] =
                *(const uint4*)&A[(size_t)(m0 + r) * K + kt + col * 8];
        }
#pragma unroll
        for (int i = 0; i < BN / 64; i++) {
            int c = i * 256 + tid;
            int r = c >> 2, col = c & 3;
            *(uint4*)&B_lds[r * 40 + col * 8] =
                *(const uint4*)&Bt[(size_t)(n0 + r) * K + kt + col * 8];
        }
        __syncthreads();
        short8 af[4], bf[NT];
#pragma unroll
        for (int mt = 0; mt < 4; mt++)
            af[mt] = *(const short8*)&A_lds[(wm * 64 + mt * 16 + l15) * 40 + quad * 8];
#pragma unroll
        for (int nt = 0; nt < NT; nt++)
            bf[nt] = *(const short8*)&B_lds[(wn * (BN / 2) + nt * 16 + l15) * 40 + quad * 8];
#pragma unroll
        for (int mt = 0; mt < 4; mt++)
#pragma unroll
            for (int nt = 0; nt < NT; nt++)
                acc[mt][nt] = __builtin_amdgcn_mfma_f32_16x16x32_bf16(af[mt], bf[nt], acc[mt][nt], 0, 0, 0);
    }

#pragma unroll
    for (int nt = 0; nt < NT; nt++) {
        int col = n0 + wn * (BN / 2) + nt * 16 + l15;
        float bs = bias[col];
#pragma unroll
        for (int mt = 0; mt < 4; mt++) {
            int row = m0 + wm * 64 + mt * 16 + quad * 4;
#pragma unroll
            for (int r = 0; r < 4; r++) {
                float v = acc[mt][nt][r] + bs;
                if (EPI == 0) {
                    ((float*)Cout)[(size_t)(row + r) * N + col] = v;
                } else {
                    int rr = row + r;
                    int bi = rr >> 10, ni = rr & 1023;
                    int h = col >> 9, d = col & 511;
                    ((u16*)Cout)[(((size_t)((bi * 8 + h)) * 1024 + ni)) * 512 + d] = f2bf(v);
                }
            }
        }
    }
}

// ---------------------------------------------------------------------------
// S-pass: P[M,4096] = exp2(sc * A[M,512] * Kb[4096,512]^T), denom[row] += rowsum.
// m97 structure: BM=128, BN=128, K=512. grid=(32, M/128). A/denom pre-offset by bh0.
__global__ __launch_bounds__(256, 2) void s_exp_gemm_kernel(const u16* __restrict__ A,
                                                            const u16* __restrict__ Bt,
                                                            u16* __restrict__ P,
                                                            float* __restrict__ denom) {
    __shared__ __align__(16) u16 A_lds[128 * 40];
    __shared__ __align__(16) u16 B_lds[128 * 40];
    int tid = threadIdx.x;
    int w = tid >> 6, lane = tid & 63, l15 = lane & 15, quad = lane >> 4;
    int wm = w >> 1, wn = w & 1;
    int n0 = blockIdx.x * 128, m0 = blockIdx.y * 128;

    f32x4 acc[4][4];
#pragma unroll
    for (int i = 0; i < 4; i++)
#pragma unroll
        for (int j = 0; j < 4; j++) acc[i][j] = (f32x4)(0.0f);

    for (int kt = 0; kt < 512; kt += 32) {
        __syncthreads();
#pragma unroll
        for (int i = 0; i < 2; i++) {
            int c = i * 256 + tid;
            int r = c >> 2, col = c & 3;
            *(uint4*)&A_lds[r * 40 + col * 8] =
                *(const uint4*)&A[(size_t)(m0 + r) * 512 + kt + col * 8];
            *(uint4*)&B_lds[r * 40 + col * 8] =
                *(const uint4*)&Bt[(size_t)(n0 + r) * 512 + kt + col * 8];
        }
        __syncthreads();
        short8 af[4], bf[4];
#pragma unroll
        for (int mt = 0; mt < 4; mt++)
            af[mt] = *(const short8*)&A_lds[(wm * 64 + mt * 16 + l15) * 40 + quad * 8];
#pragma unroll
        for (int nt = 0; nt < 4; nt++)
            bf[nt] = *(const short8*)&B_lds[(wn * 64 + nt * 16 + l15) * 40 + quad * 8];
#pragma unroll
        for (int mt = 0; mt < 4; mt++)
#pragma unroll
            for (int nt = 0; nt < 4; nt++)
                acc[mt][nt] = __builtin_amdgcn_mfma_f32_16x16x32_bf16(af[mt], bf[nt], acc[mt][nt], 0, 0, 0);
    }

    const float sc = 0.06375871826463886f; // log2(e)/sqrt(512)
#pragma unroll
    for (int mt = 0; mt < 4; mt++) {
#pragma unroll
        for (int r = 0; r < 4; r++) {
            int row = m0 + wm * 64 + mt * 16 + quad * 4 + r;
            float rs = 0.f;
#pragma unroll
            for (int nt = 0; nt < 4; nt++) {
                int col = n0 + wn * 64 + nt * 16 + l15;
                float p = exp2f(acc[mt][nt][r] * sc);
                rs += p;
                P[(size_t)row * 4096 + col] = f2bf(p);
            }
            rs += __shfl_xor(rs, 1); rs += __shfl_xor(rs, 2);
            rs += __shfl_xor(rs, 4); rs += __shfl_xor(rs, 8);
            if (l15 == 0) atomicAdd(&denom[row], rs);
        }
    }
}

// ---------------------------------------------------------------------------
// PV-pass: rv = (P[M,4096] * Vtb[512,4096]^T) / denom, scattered to
// rv[b*1024+n, h*512+d] with global row gr = bh0*1024 + local row.
// BM=128, BN=128, K=4096. grid=(4, M/128). P/denom pre-offset by bh0.
__global__ __launch_bounds__(256, 2) void pv_gemm_kernel(const u16* __restrict__ A,
                                                         const u16* __restrict__ Bt,
                                                         const float* __restrict__ denom,
                                                         u16* __restrict__ rv,
                                                         int bh0) {
    __shared__ __align__(16) u16 A_lds[128 * 40];
    __shared__ __align__(16) u16 B_lds[128 * 40];
    int tid = threadIdx.x;
    int w = tid >> 6, lane = tid & 63, l15 = lane & 15, quad = lane >> 4;
    int wm = w >> 1, wn = w & 1;
    int n0 = blockIdx.x * 128, m0 = blockIdx.y * 128;

    f32x4 acc[4][4];
#pragma unroll
    for (int i = 0; i < 4; i++)
#pragma unroll
        for (int j = 0; j < 4; j++) acc[i][j] = (f32x4)(0.0f);

    for (int kt = 0; kt < 4096; kt += 32) {
        __syncthreads();
#pragma unroll
        for (int i = 0; i < 2; i++) {
            int c = i * 256 + tid;
            int r = c >> 2, col = c & 3;
            *(uint4*)&A_lds[r * 40 + col * 8] =
                *(const uint4*)&A[(size_t)(m0 + r) * 4096 + kt + col * 8];
            *(uint4*)&B_lds[r * 40 + col * 8] =
                *(const uint4*)&Bt[(size_t)(n0 + r) * 4096 + kt + col * 8];
        }
        __syncthreads();
        short8 af[4], bf[4];
#pragma unroll
        for (int mt = 0; mt < 4; mt++)
            af[mt] = *(const short8*)&A_lds[(wm * 64 + mt * 16 + l15) * 40 + quad * 8];
#pragma unroll
        for (int nt = 0; nt < 4; nt++)
            bf[nt] = *(const short8*)&B_lds[(wn * 64 + nt * 16 + l15) * 40 + quad * 8];
#pragma unroll
        for (int mt = 0; mt < 4; mt++)
#pragma unroll
            for (int nt = 0; nt < 4; nt++)
                acc[mt][nt] = __builtin_amdgcn_mfma_f32_16x16x32_bf16(af[mt], bf[nt], acc[mt][nt], 0, 0, 0);
    }

#pragma unroll
    for (int mt = 0; mt < 4; mt++) {
#pragma unroll
        for (int r = 0; r < 4; r++) {
            int lr = m0 + wm * 64 + mt * 16 + quad * 4 + r;
            int gr = bh0 * 1024 + lr;
            float inv = 1.0f / denom[lr];
            int b = gr >> 13, h = (gr >> 10) & 7, n = gr & 1023;
            size_t base = ((size_t)(b * 1024 + n)) * 4096 + h * 512;
#pragma unroll
            for (int nt = 0; nt < 4; nt++) {
                int col = n0 + wn * 64 + nt * 16 + l15;
                rv[base + col] = f2bf(acc[mt][nt][r] * inv);
            }
        }
    }
}

// ---------------------------------------------------------------------------
// sims argmax v2 (fp32 — bf16 would misrank slots). mnT is [512 k][4096 m].
// grid = dim3(64, 8): 64 write-groups of 16 wi x 8 m-chunks of 512. block=256.
// Thread: 16 wi x 2 m accumulators; k unrolled x4 with float4 LDS broadcasts.
// 512 blocks -> 2 blocks/CU (2 waves/SIMD) for latency hiding; VALU-bound.
__global__ __launch_bounds__(256) void sims_argmax_kernel(const float* __restrict__ wk,
                                                          const float* __restrict__ mnT,
                                                          u64* __restrict__ amax) {
    __shared__ __align__(16) float wkl[16][512];
    int tid = threadIdx.x;
    int w0 = blockIdx.x * 16, m0 = blockIdx.y * 512;
    for (int i = tid; i < 16 * 512; i += 256)
        wkl[i >> 9][i & 511] = wk[(size_t)w0 * 512 + i];
    __syncthreads();
    int mbase = m0 + tid * 2;
    float acc0[16], acc1[16];
#pragma unroll
    for (int i = 0; i < 16; i++) { acc0[i] = 0.f; acc1[i] = 0.f; }
    for (int k = 0; k < 512; k += 4) {
        float2 v0 = *(const float2*)&mnT[(size_t)(k + 0) * 4096 + mbase];
        float2 v1 = *(const float2*)&mnT[(size_t)(k + 1) * 4096 + mbase];
        float2 v2 = *(const float2*)&mnT[(size_t)(k + 2) * 4096 + mbase];
        float2 v3 = *(const float2*)&mnT[(size_t)(k + 3) * 4096 + mbase];
#pragma unroll
        for (int wi = 0; wi < 16; wi++) {
            float4 s = *(const float4*)&wkl[wi][k];
            acc0[wi] += s.x * v0.x + s.y * v1.x + s.z * v2.x + s.w * v3.x;
            acc1[wi] += s.x * v0.y + s.y * v1.y + s.z * v2.y + s.w * v3.y;
        }
    }
#pragma unroll
    for (int wi = 0; wi < 16; wi++) {
        u64 best = 0;
        {
            u32 bb = __float_as_uint(acc0[wi]);
            bb = (bb & 0x80000000u) ? ~bb : (bb | 0x80000000u);
            best = ((u64)bb << 32) | (u32)(4095 - mbase);       // ties -> smaller m wins
        }
        {
            u32 bb = __float_as_uint(acc1[wi]);
            bb = (bb & 0x80000000u) ? ~bb : (bb | 0x80000000u);
            u64 key = ((u64)bb << 32) | (u32)(4095 - (mbase + 1));
            best = best > key ? best : key;
        }
        atomicMax(&amax[w0 + wi], best);
    }
}

// ---------------------------------------------------------------------------
// decode idx from amax keys, build per-slot chains (next[], heads[], count).
// single block of 1024 threads.
__global__ void chains_build_kernel(const u64* __restrict__ amax, int* __restrict__ idx,
                                    int* __restrict__ nxt, int* __restrict__ heads,
                                    int* __restrict__ count) {
    int i = threadIdx.x;
    idx[i] = 4095 - (int)(u32)(amax[i] & 0xFFFFFFFFull);
    __syncthreads();
    int my = idx[i];
    int nx = -1;
    for (int j = i + 1; j < 1024; j++)
        if (idx[j] == my) { nx = j; break; }
    nxt[i] = nx;
    bool head = true;
    for (int j = 0; j < i; j++)
        if (idx[j] == my) { head = false; break; }
    if (head) {
        int p = atomicAdd(count, 1);
        heads[p] = i;
    }
}

// ---------------------------------------------------------------------------
// G1[i][j] = write_keys[i] . Wg[0:512, j] + bg[j]   (fp32). 8 rows/block, grid=128.
__global__ __launch_bounds__(256) void g1_gemm_kernel(const float* __restrict__ wk,
                                                      const float* __restrict__ Wg,
                                                      const float* __restrict__ bg,
                                                      float* __restrict__ G1) {
    __shared__ float wkl[8][512];
    int tid = threadIdx.x;
    int i0 = blockIdx.x * 8;
    for (int i = tid; i < 8 * 512; i += 256) wkl[i >> 9][i & 511] = wk[(size_t)i0 * 512 + i];
    __syncthreads();
    float a0[8], a1[8];
#pragma unroll
    for (int i = 0; i < 8; i++) { a0[i] = 0.f; a1[i] = 0.f; }
    for (int c = 0; c < 512; c++) {
        float w0 = Wg[(size_t)c * 512 + tid];
        float w1 = Wg[(size_t)c * 512 + tid + 256];
#pragma unroll
        for (int ii = 0; ii < 8; ii++) {
            float s = wkl[ii][c];
            a0[ii] += s * w0; a1[ii] += s * w1;
        }
    }
    float b0 = bg[tid], b1 = bg[tid + 256];
#pragma unroll
    for (int ii = 0; ii < 8; ii++) {
        G1[(size_t)(i0 + ii) * 512 + tid] = a0[ii] + b0;
        G1[(size_t)(i0 + ii) * 512 + tid + 256] = a1[ii] + b1;
    }
}

// ---------------------------------------------------------------------------
// Apply per-slot chains sequentially (fp32). block = 256 threads per chain.
__global__ __launch_bounds__(256) void chain_apply_kernel(const int* __restrict__ heads,
                                                          const int* __restrict__ count,
                                                          const int* __restrict__ idx,
                                                          const int* __restrict__ nxt,
                                                          const float* __restrict__ G1,
                                                          const float* __restrict__ Wg,
                                                          const float* __restrict__ wk,
                                                          const float* __restrict__ wv,
                                                          const float* __restrict__ mk,
                                                          const float* __restrict__ mv,
                                                          float* __restrict__ outK,
                                                          float* __restrict__ outV) {
    int b = blockIdx.x;
    if (b >= *count) return;
    int i = heads[b];
    int s = idx[i];
    int tid = threadIdx.x;
    __shared__ float V[512];
    V[tid] = mv[(size_t)s * 512 + tid];
    V[tid + 256] = mv[(size_t)s * 512 + tid + 256];
    float k0 = mk[(size_t)s * 512 + tid], k1 = mk[(size_t)s * 512 + tid + 256];
    __syncthreads();
    while (i >= 0) {
        float a0 = G1[(size_t)i * 512 + tid], a1 = G1[(size_t)i * 512 + tid + 256];
        for (int c = 0; c < 512; c++) {
            float vc = V[c];
            a0 += vc * Wg[(size_t)(512 + c) * 512 + tid];
            a1 += vc * Wg[(size_t)(512 + c) * 512 + tid + 256];
        }
        float g0 = 1.f / (1.f + __expf(-a0));
        float g1 = 1.f / (1.f + __expf(-a1));
        __syncthreads(); // everyone finished reading V
        k0 = g0 * wk[(size_t)i * 512 + tid] + (1.f - g0) * k0;
        k1 = g1 * wk[(size_t)i * 512 + tid + 256] + (1.f - g1) * k1;
        V[tid] = g0 * wv[(size_t)i * 512 + tid] + (1.f - g0) * V[tid];
        V[tid + 256] = g1 * wv[(size_t)i * 512 + tid + 256] + (1.f - g1) * V[tid + 256];
        __syncthreads();
        i = nxt[i];
    }
    outK[(size_t)s * 512 + tid] = k0;
    outK[(size_t)s * 512 + tid + 256] = k1;
    outV[(size_t)s * 512 + tid] = V[tid];
    outV[(size_t)s * 512 + tid + 256] = V[tid + 256];
}

// ---------------------------------------------------------------------------
extern "C" void kernel_launch(void* const* d_in, const int* in_sizes, int n_in,
                              void* d_out, int out_size, void* d_ws, size_t ws_size,
                              hipStream_t stream) {
    const float* queries = (const float*)d_in[0]; // [4,1024,512]
    const float* wkeys   = (const float*)d_in[1]; // [1024,512]
    const float* wvals   = (const float*)d_in[2]; // [1024,512]
    const float* mkeys   = (const float*)d_in[3]; // [4096,512]
    const float* mvals   = (const float*)d_in[4]; // [4096,512]
    const float* Wq      = (const float*)d_in[5]; // [512,4096]
    const float* bq      = (const float*)d_in[6]; // [4096]
    const float* Wvp     = (const float*)d_in[7]; // [4096,512]
    const float* bvp     = (const float*)d_in[8]; // [512]
    const float* Wg      = (const float*)d_in[9]; // [1024,512]
    const float* bg      = (const float*)d_in[10];// [512]

    float* out_read = (float*)d_out;              // [4,1024,512]
    float* out_k = out_read + (size_t)4 * 1024 * 512; // [4096,512]
    float* out_v = out_k + (size_t)4096 * 512;        // [4096,512]

    char* ws = (char*)d_ws;
    const size_t MB = 1024 * 1024;
    // region [0, 4MB): Qbf during prep/q-proj, then reused for meta + denom
    u16* Qbf  = (u16*)(ws);            // 4 MB   queries bf16 [4096,512]
    u16* WqT  = (u16*)(ws + 4 * MB);   // 4 MB   Wq^T bf16 [4096,512]
    u16* Qatt = (u16*)(ws + 8 * MB);   // 32 MB  q bf16 [(b,h),n,d] = [32768,512]
    u16* Kb   = (u16*)(ws + 40 * MB);  // 4 MB   mem_keys bf16 [4096,512]
    u16* Vtb  = (u16*)(ws + 44 * MB);  // 4 MB   mem_values^T bf16 [512,4096]
    u16* rv   = (u16*)(ws + 48 * MB);  // 32 MB  attention out bf16 [4096,4096]
    u16* WvpT = (u16*)(ws + 80 * MB);  // 4 MB   Wvp^T bf16 [512,4096]
    float* mn  = (float*)(ws + 84 * MB); // 8 MB normalized mem_keys [4096,512]
    float* G1  = (float*)(ws + 92 * MB); // 2 MB gate pre from write_keys [1024,512]
    float* mnT = (float*)(ws + 94 * MB); // 8 MB normalized keys transposed [512,4096]
    // meta + denom overlay the dead Qbf region (valid after q-proj completes)
    u64* amax   = (u64*)(ws);                   // 8 KB
    int* count  = (int*)(ws + 8192);            // 4 B
    int* idx    = (int*)(ws + 8192 + 256);      // 4 KB
    int* nxt    = (int*)(ws + 8192 + 256 + 4096);   // 4 KB
    int* heads  = (int*)(ws + 8192 + 256 + 8192);   // 4 KB
    float* denom = (float*)(ws + 32 * 1024);    // 128 KB [32768]
    // P overlays the dead mn/G1/mnT region (valid after chain_apply completes)
    u16* P = (u16*)(ws + 84 * MB);              // up to 256 MB [G*1024, 4096]
    (void)in_sizes; (void)n_in; (void)out_size;

    // chunk size over bh: P needs G*8MB starting at 84MB
    size_t avail = (ws_size > 84 * MB) ? ws_size - 84 * MB : 0;
    int G = 2; // proven-safe floor: 16 MB fits in [84MB, 100MB) (ws >= 102MB)
    for (int g = 32; g >= 2; g >>= 1)
        if ((size_t)g * 8 * MB <= avail) { G = g; break; }

    // new_keys / new_values start as copies of mem_keys / mem_values
    hipMemcpyAsync(out_k, mkeys, (size_t)4096 * 512 * 4, hipMemcpyDeviceToDevice, stream);
    hipMemcpyAsync(out_v, mvals, (size_t)4096 * 512 * 4, hipMemcpyDeviceToDevice, stream);

    // ---- prep casts / transposes ----
    cast_bf16_kernel<<<2048, 256, 0, stream>>>(queries, Qbf);
    cast_transpose_kernel<<<dim3(4096 / 32, 512 / 32), 256, 0, stream>>>(Wq, WqT, 512, 4096);
    cast_transpose_kernel<<<dim3(512 / 32, 4096 / 32), 256, 0, stream>>>(Wvp, WvpT, 4096, 512);
    cast_transpose_kernel<<<dim3(512 / 32, 4096 / 32), 256, 0, stream>>>(mvals, Vtb, 4096, 512);
    key_prep_kernel<<<4096, 256, 0, stream>>>(mkeys, mn, Kb);
    transpose_f32_kernel<<<dim3(512 / 32, 4096 / 32), 256, 0, stream>>>(mn, mnT, 4096, 512);

    // ---- q-proj (last user of Qbf/WqT) ----
    gemm_bt_kernel<128, 1><<<dim3(32, 32), 256, 0, stream>>>(Qbf, WqT, bq, (void*)Qatt, 4096, 4096, 512);

    // ---- write path (fp32), frees mn/G1/mnT for the P overlay afterwards ----
    hipMemsetAsync(ws, 0, 8192 + 256, stream);          // amax + count (Qbf now dead)
    hipMemsetAsync(denom, 0, 32768 * 4, stream);        // denom
    sims_argmax_kernel<<<dim3(64, 8), 256, 0, stream>>>(wkeys, mnT, amax);
    chains_build_kernel<<<1, 1024, 0, stream>>>(amax, idx, nxt, heads, count);
    g1_gemm_kernel<<<128, 256, 0, stream>>>(wkeys, Wg, bg, G1);
    chain_apply_kernel<<<1024, 256, 0, stream>>>(heads, count, idx, nxt, G1, Wg,
                                                 wkeys, wvals, mkeys, mvals, out_k, out_v);

    // ---- attention as two GEMM passes, chunked over bh ----
    for (int bh0 = 0; bh0 < 32; bh0 += G) {
        const u16* Achunk = Qatt + (size_t)bh0 * 1024 * 512;
        float* dchunk = denom + bh0 * 1024;
        s_exp_gemm_kernel<<<dim3(32, G * 8), 256, 0, stream>>>(Achunk, Kb, P, dchunk);
        pv_gemm_kernel<<<dim3(4, G * 8), 256, 0, stream>>>(P, Vtb, dchunk, rv, bh0);
    }

    // ---- out-proj ----
    gemm_bt_kernel<64, 0><<<dim3(8, 32), 256, 0, stream>>>(rv, WvpT, bvp, (void*)out_read, 4096, 512, 4096);
}

// Round 5
// 1033.390 us; speedup vs baseline: 1.0680x; 1.0680x over previous
//
#include <hip/hip_runtime.h>
#include <cstdint>
#include <cstddef>

typedef __attribute__((ext_vector_type(8))) short short8;
typedef __attribute__((ext_vector_type(4))) float f32x4;
typedef unsigned short u16;
typedef unsigned int u32;
typedef unsigned long long u64;

__device__ __forceinline__ u16 f2bf(float f) {
    u32 u = __float_as_uint(f);
    u = (u + 0x7FFFu + ((u >> 16) & 1u)) >> 16;
    return (u16)u;
}

// ---------------------------------------------------------------------------
// Elementwise cast fp32 -> bf16 (vectorized x4). n must be multiple of 4.
__global__ void cast_bf16_kernel(const float* __restrict__ src, u16* __restrict__ dst) {
    int i = blockIdx.x * 256 + threadIdx.x;
    float4 v = *((const float4*)src + i);
    ushort4 r;
    r.x = f2bf(v.x); r.y = f2bf(v.y); r.z = f2bf(v.z); r.w = f2bf(v.w);
    *((ushort4*)dst + i) = r;
}

// ---------------------------------------------------------------------------
// Tiled transpose: src fp32 [R][C] -> dst bf16 [C][R]. grid=(C/32, R/32), block=256.
__global__ void cast_transpose_kernel(const float* __restrict__ src, u16* __restrict__ dst,
                                      int R, int C) {
    __shared__ float tile[32][33];
    int tx = threadIdx.x & 31, ty = threadIdx.x >> 5;
    int c0 = blockIdx.x * 32, r0 = blockIdx.y * 32;
#pragma unroll
    for (int j = 0; j < 4; j++)
        tile[ty + 8 * j][tx] = src[(size_t)(r0 + ty + 8 * j) * C + c0 + tx];
    __syncthreads();
#pragma unroll
    for (int j = 0; j < 4; j++)
        dst[(size_t)(c0 + ty + 8 * j) * R + r0 + tx] = f2bf(tile[tx][ty + 8 * j]);
}

// Tiled transpose: src fp32 [R][C] -> dst fp32 [C][R].
__global__ void transpose_f32_kernel(const float* __restrict__ src, float* __restrict__ dst,
                                     int R, int C) {
    __shared__ float tile[32][33];
    int tx = threadIdx.x & 31, ty = threadIdx.x >> 5;
    int c0 = blockIdx.x * 32, r0 = blockIdx.y * 32;
#pragma unroll
    for (int j = 0; j < 4; j++)
        tile[ty + 8 * j][tx] = src[(size_t)(r0 + ty + 8 * j) * C + c0 + tx];
    __syncthreads();
#pragma unroll
    for (int j = 0; j < 4; j++)
        dst[(size_t)(c0 + ty + 8 * j) * R + r0 + tx] = tile[tx][ty + 8 * j];
}

// ---------------------------------------------------------------------------
// mem_keys -> mn (fp32 row-normalized, for argmax) and Kb (bf16 raw, for attention)
__global__ __launch_bounds__(256) void key_prep_kernel(const float* __restrict__ mk,
                                                       float* __restrict__ mn,
                                                       u16* __restrict__ Kb) {
    int row = blockIdx.x, tid = threadIdx.x;
    const float* src = mk + (size_t)row * 512;
    float x0 = src[tid], x1 = src[tid + 256];
    float ss = x0 * x0 + x1 * x1;
#pragma unroll
    for (int m = 1; m < 64; m <<= 1) ss += __shfl_xor(ss, m);
    __shared__ float sred[4];
    if ((tid & 63) == 0) sred[tid >> 6] = ss;
    __syncthreads();
    float tot = sred[0] + sred[1] + sred[2] + sred[3];
    float inv = 1.0f / fmaxf(sqrtf(tot), 1e-8f);
    mn[(size_t)row * 512 + tid] = x0 * inv;
    mn[(size_t)row * 512 + tid + 256] = x1 * inv;
    Kb[(size_t)row * 512 + tid] = f2bf(x0);
    Kb[(size_t)row * 512 + tid + 256] = f2bf(x1);
}

// ---------------------------------------------------------------------------
// GEMM: C[M,N] = A[M,K] * Bt[N,K]^T + bias[N].  bf16 inputs, fp32 accumulate.
// BM=128 fixed, BN template (128 or 64). block=256 (4 waves, 2x2 quadrants).
// EPI==0: write fp32 C row-major [M,N].
// EPI==1: q-proj permute: row=(b*1024+n), col=(h*512+d) -> Qatt bf16 [((b*8+h)*1024+n)*512+d]
template <int BN, int EPI>
__global__ __launch_bounds__(256, 2) void gemm_bt_kernel(const u16* __restrict__ A,
                                                         const u16* __restrict__ Bt,
                                                         const float* __restrict__ bias,
                                                         void* __restrict__ Cout,
                                                         int M, int N, int K) {
    constexpr int NT = BN / 32;
    __shared__ __align__(16) u16 A_lds[128 * 40];
    __shared__ __align__(16) u16 B_lds[BN * 40];
    int tid = threadIdx.x;
    int w = tid >> 6, lane = tid & 63, l15 = lane & 15, quad = lane >> 4;
    int wm = w >> 1, wn = w & 1;
    int n0 = blockIdx.x * BN, m0 = blockIdx.y * 128;

    f32x4 acc[4][NT];
#pragma unroll
    for (int i = 0; i < 4; i++)
#pragma unroll
        for (int j = 0; j < NT; j++) acc[i][j] = (f32x4)(0.0f);

    for (int kt = 0; kt < K; kt += 32) {
        __syncthreads();
#pragma unroll
        for (int i = 0; i < 2; i++) {
            int c = i * 256 + tid;
            int r = c >> 2, col = c & 3;
            *(uint4*)&A_lds[r * 40 + col * 8] =
                *(const uint4*)&A[(size_t)(m0 + r) * K + kt + col * 8];
        }
#pragma unroll
        for (int i = 0; i < BN / 64; i++) {
            int c = i * 256 + tid;
            int r = c >> 2, col = c & 3;
            *(uint4*)&B_lds[r * 40 + col * 8] =
                *(const uint4*)&Bt[(size_t)(n0 + r) * K + kt + col * 8];
        }
        __syncthreads();
        short8 af[4], bf[NT];
#pragma unroll
        for (int mt = 0; mt < 4; mt++)
            af[mt] = *(const short8*)&A_lds[(wm * 64 + mt * 16 + l15) * 40 + quad * 8];
#pragma unroll
        for (int nt = 0; nt < NT; nt++)
            bf[nt] = *(const short8*)&B_lds[(wn * (BN / 2) + nt * 16 + l15) * 40 + quad * 8];
#pragma unroll
        for (int mt = 0; mt < 4; mt++)
#pragma unroll
            for (int nt = 0; nt < NT; nt++)
                acc[mt][nt] = __builtin_amdgcn_mfma_f32_16x16x32_bf16(af[mt], bf[nt], acc[mt][nt], 0, 0, 0);
    }

#pragma unroll
    for (int nt = 0; nt < NT; nt++) {
        int col = n0 + wn * (BN / 2) + nt * 16 + l15;
        float bs = bias[col];
#pragma unroll
        for (int mt = 0; mt < 4; mt++) {
            int row = m0 + wm * 64 + mt * 16 + quad * 4;
#pragma unroll
            for (int r = 0; r < 4; r++) {
                float v = acc[mt][nt][r] + bs;
                if (EPI == 0) {
                    ((float*)Cout)[(size_t)(row + r) * N + col] = v;
                } else {
                    int rr = row + r;
                    int bi = rr >> 10, ni = rr & 1023;
                    int h = col >> 9, d = col & 511;
                    ((u16*)Cout)[(((size_t)((bi * 8 + h)) * 1024 + ni)) * 512 + d] = f2bf(v);
                }
            }
        }
    }
}

// ---------------------------------------------------------------------------
// S-pass: P[M,4096] = exp2(sc * A[M,512] * Kb[4096,512]^T), denom[row] += rowsum.
// m97 structure: BM=128, BN=128, K=512. grid=(32, M/128). A/denom pre-offset by bh0.
__global__ __launch_bounds__(256, 2) void s_exp_gemm_kernel(const u16* __restrict__ A,
                                                            const u16* __restrict__ Bt,
                                                            u16* __restrict__ P,
                                                            float* __restrict__ denom) {
    __shared__ __align__(16) u16 A_lds[128 * 40];
    __shared__ __align__(16) u16 B_lds[128 * 40];
    int tid = threadIdx.x;
    int w = tid >> 6, lane = tid & 63, l15 = lane & 15, quad = lane >> 4;
    int wm = w >> 1, wn = w & 1;
    int n0 = blockIdx.x * 128, m0 = blockIdx.y * 128;

    f32x4 acc[4][4];
#pragma unroll
    for (int i = 0; i < 4; i++)
#pragma unroll
        for (int j = 0; j < 4; j++) acc[i][j] = (f32x4)(0.0f);

    for (int kt = 0; kt < 512; kt += 32) {
        __syncthreads();
#pragma unroll
        for (int i = 0; i < 2; i++) {
            int c = i * 256 + tid;
            int r = c >> 2, col = c & 3;
            *(uint4*)&A_lds[r * 40 + col * 8] =
                *(const uint4*)&A[(size_t)(m0 + r) * 512 + kt + col * 8];
            *(uint4*)&B_lds[r * 40 + col * 8] =
                *(const uint4*)&Bt[(size_t)(n0 + r) * 512 + kt + col * 8];
        }
        __syncthreads();
        short8 af[4], bf[4];
#pragma unroll
        for (int mt = 0; mt < 4; mt++)
            af[mt] = *(const short8*)&A_lds[(wm * 64 + mt * 16 + l15) * 40 + quad * 8];
#pragma unroll
        for (int nt = 0; nt < 4; nt++)
            bf[nt] = *(const short8*)&B_lds[(wn * 64 + nt * 16 + l15) * 40 + quad * 8];
#pragma unroll
        for (int mt = 0; mt < 4; mt++)
#pragma unroll
            for (int nt = 0; nt < 4; nt++)
                acc[mt][nt] = __builtin_amdgcn_mfma_f32_16x16x32_bf16(af[mt], bf[nt], acc[mt][nt], 0, 0, 0);
    }

    const float sc = 0.06375871826463886f; // log2(e)/sqrt(512)
#pragma unroll
    for (int mt = 0; mt < 4; mt++) {
#pragma unroll
        for (int r = 0; r < 4; r++) {
            int row = m0 + wm * 64 + mt * 16 + quad * 4 + r;
            float rs = 0.f;
#pragma unroll
            for (int nt = 0; nt < 4; nt++) {
                int col = n0 + wn * 64 + nt * 16 + l15;
                float p = exp2f(acc[mt][nt][r] * sc);
                rs += p;
                P[(size_t)row * 4096 + col] = f2bf(p);
            }
            rs += __shfl_xor(rs, 1); rs += __shfl_xor(rs, 2);
            rs += __shfl_xor(rs, 4); rs += __shfl_xor(rs, 8);
            if (l15 == 0) atomicAdd(&denom[row], rs);
        }
    }
}

// ---------------------------------------------------------------------------
// PV-pass: rv = (P[M,4096] * Vtb[512,4096]^T) / denom, scattered to
// rv[b*1024+n, h*512+d] with global row gr = bh0*1024 + local row.
// BM=128, BN=128, K=4096. grid=(4, M/128). P/denom pre-offset by bh0.
__global__ __launch_bounds__(256, 2) void pv_gemm_kernel(const u16* __restrict__ A,
                                                         const u16* __restrict__ Bt,
                                                         const float* __restrict__ denom,
                                                         u16* __restrict__ rv,
                                                         int bh0) {
    __shared__ __align__(16) u16 A_lds[128 * 40];
    __shared__ __align__(16) u16 B_lds[128 * 40];
    int tid = threadIdx.x;
    int w = tid >> 6, lane = tid & 63, l15 = lane & 15, quad = lane >> 4;
    int wm = w >> 1, wn = w & 1;
    int n0 = blockIdx.x * 128, m0 = blockIdx.y * 128;

    f32x4 acc[4][4];
#pragma unroll
    for (int i = 0; i < 4; i++)
#pragma unroll
        for (int j = 0; j < 4; j++) acc[i][j] = (f32x4)(0.0f);

    for (int kt = 0; kt < 4096; kt += 32) {
        __syncthreads();
#pragma unroll
        for (int i = 0; i < 2; i++) {
            int c = i * 256 + tid;
            int r = c >> 2, col = c & 3;
            *(uint4*)&A_lds[r * 40 + col * 8] =
                *(const uint4*)&A[(size_t)(m0 + r) * 4096 + kt + col * 8];
            *(uint4*)&B_lds[r * 40 + col * 8] =
                *(const uint4*)&Bt[(size_t)(n0 + r) * 4096 + kt + col * 8];
        }
        __syncthreads();
        short8 af[4], bf[4];
#pragma unroll
        for (int mt = 0; mt < 4; mt++)
            af[mt] = *(const short8*)&A_lds[(wm * 64 + mt * 16 + l15) * 40 + quad * 8];
#pragma unroll
        for (int nt = 0; nt < 4; nt++)
            bf[nt] = *(const short8*)&B_lds[(wn * 64 + nt * 16 + l15) * 40 + quad * 8];
#pragma unroll
        for (int mt = 0; mt < 4; mt++)
#pragma unroll
            for (int nt = 0; nt < 4; nt++)
                acc[mt][nt] = __builtin_amdgcn_mfma_f32_16x16x32_bf16(af[mt], bf[nt], acc[mt][nt], 0, 0, 0);
    }

#pragma unroll
    for (int mt = 0; mt < 4; mt++) {
#pragma unroll
        for (int r = 0; r < 4; r++) {
            int lr = m0 + wm * 64 + mt * 16 + quad * 4 + r;
            int gr = bh0 * 1024 + lr;
            float inv = 1.0f / denom[lr];
            int b = gr >> 13, h = (gr >> 10) & 7, n = gr & 1023;
            size_t base = ((size_t)(b * 1024 + n)) * 4096 + h * 512;
#pragma unroll
            for (int nt = 0; nt < 4; nt++) {
                int col = n0 + wn * 64 + nt * 16 + l15;
                rv[base + col] = f2bf(acc[mt][nt][r] * inv);
            }
        }
    }
}

// ---------------------------------------------------------------------------
// sims argmax v2 (fp32 — bf16 would misrank slots). mnT is [512 k][4096 m].
// grid = dim3(64, 8): 64 write-groups of 16 wi x 8 m-chunks of 512. block=256.
// Thread: 16 wi x 2 m accumulators; k unrolled x4 with float4 LDS broadcasts.
// 512 blocks -> 2 blocks/CU (2 waves/SIMD) for latency hiding; VALU-bound.
__global__ __launch_bounds__(256) void sims_argmax_kernel(const float* __restrict__ wk,
                                                          const float* __restrict__ mnT,
                                                          u64* __restrict__ amax) {
    __shared__ __align__(16) float wkl[16][512];
    int tid = threadIdx.x;
    int w0 = blockIdx.x * 16, m0 = blockIdx.y * 512;
    for (int i = tid; i < 16 * 512; i += 256)
        wkl[i >> 9][i & 511] = wk[(size_t)w0 * 512 + i];
    __syncthreads();
    int mbase = m0 + tid * 2;
    float acc0[16], acc1[16];
#pragma unroll
    for (int i = 0; i < 16; i++) { acc0[i] = 0.f; acc1[i] = 0.f; }
    for (int k = 0; k < 512; k += 4) {
        float2 v0 = *(const float2*)&mnT[(size_t)(k + 0) * 4096 + mbase];
        float2 v1 = *(const float2*)&mnT[(size_t)(k + 1) * 4096 + mbase];
        float2 v2 = *(const float2*)&mnT[(size_t)(k + 2) * 4096 + mbase];
        float2 v3 = *(const float2*)&mnT[(size_t)(k + 3) * 4096 + mbase];
#pragma unroll
        for (int wi = 0; wi < 16; wi++) {
            float4 s = *(const float4*)&wkl[wi][k];
            acc0[wi] += s.x * v0.x + s.y * v1.x + s.z * v2.x + s.w * v3.x;
            acc1[wi] += s.x * v0.y + s.y * v1.y + s.z * v2.y + s.w * v3.y;
        }
    }
#pragma unroll
    for (int wi = 0; wi < 16; wi++) {
        u64 best = 0;
        {
            u32 bb = __float_as_uint(acc0[wi]);
            bb = (bb & 0x80000000u) ? ~bb : (bb | 0x80000000u);
            best = ((u64)bb << 32) | (u32)(4095 - mbase);       // ties -> smaller m wins
        }
        {
            u32 bb = __float_as_uint(acc1[wi]);
            bb = (bb & 0x80000000u) ? ~bb : (bb | 0x80000000u);
            u64 key = ((u64)bb << 32) | (u32)(4095 - (mbase + 1));
            best = best > key ? best : key;
        }
        atomicMax(&amax[w0 + wi], best);
    }
}

// ---------------------------------------------------------------------------
// chains_build v2: decode idx, build per-slot chains. 16 blocks x 64 threads;
// every block mirrors all 1024 decoded indices in LDS, wave b handles
// i in [64b, 64b+64). Scans are LDS reads (~1100 iters/wave, parallel on 16 CUs)
// instead of the old single-block global-latency scan (152 us -> ~5 us).
// heads[] fill order is arbitrary (atomicAdd across blocks) — chains are
// independent in chain_apply, so order doesn't matter.
__global__ __launch_bounds__(64) void chains_build_kernel(const u64* __restrict__ amax,
                                                          int* __restrict__ idx,
                                                          int* __restrict__ nxt,
                                                          int* __restrict__ heads,
                                                          int* __restrict__ count) {
    __shared__ int sidx[1024];
    int tid = threadIdx.x;
    for (int j = tid; j < 1024; j += 64)
        sidx[j] = 4095 - (int)(u32)(amax[j] & 0xFFFFFFFFull);
    __syncthreads();
    int i = blockIdx.x * 64 + tid;
    int my = sidx[i];
    idx[i] = my;
    int nx = -1;
    for (int j = i + 1; j < 1024; j++)
        if (sidx[j] == my) { nx = j; break; }
    nxt[i] = nx;
    bool head = true;
    for (int j = 0; j < i; j++)
        if (sidx[j] == my) { head = false; break; }
    if (head) {
        int p = atomicAdd(count, 1);
        heads[p] = i;
    }
}

// ---------------------------------------------------------------------------
// G1[i][j] = write_keys[i] . Wg[0:512, j] + bg[j]   (fp32). 8 rows/block, grid=128.
__global__ __launch_bounds__(256) void g1_gemm_kernel(const float* __restrict__ wk,
                                                      const float* __restrict__ Wg,
                                                      const float* __restrict__ bg,
                                                      float* __restrict__ G1) {
    __shared__ float wkl[8][512];
    int tid = threadIdx.x;
    int i0 = blockIdx.x * 8;
    for (int i = tid; i < 8 * 512; i += 256) wkl[i >> 9][i & 511] = wk[(size_t)i0 * 512 + i];
    __syncthreads();
    float a0[8], a1[8];
#pragma unroll
    for (int i = 0; i < 8; i++) { a0[i] = 0.f; a1[i] = 0.f; }
    for (int c = 0; c < 512; c++) {
        float w0 = Wg[(size_t)c * 512 + tid];
        float w1 = Wg[(size_t)c * 512 + tid + 256];
#pragma unroll
        for (int ii = 0; ii < 8; ii++) {
            float s = wkl[ii][c];
            a0[ii] += s * w0; a1[ii] += s * w1;
        }
    }
    float b0 = bg[tid], b1 = bg[tid + 256];
#pragma unroll
    for (int ii = 0; ii < 8; ii++) {
        G1[(size_t)(i0 + ii) * 512 + tid] = a0[ii] + b0;
        G1[(size_t)(i0 + ii) * 512 + tid + 256] = a1[ii] + b1;
    }
}

// ---------------------------------------------------------------------------
// Apply per-slot chains sequentially (fp32). block = 256 threads per chain.
__global__ __launch_bounds__(256) void chain_apply_kernel(const int* __restrict__ heads,
                                                          const int* __restrict__ count,
                                                          const int* __restrict__ idx,
                                                          const int* __restrict__ nxt,
                                                          const float* __restrict__ G1,
                                                          const float* __restrict__ Wg,
                                                          const float* __restrict__ wk,
                                                          const float* __restrict__ wv,
                                                          const float* __restrict__ mk,
                                                          const float* __restrict__ mv,
                                                          float* __restrict__ outK,
                                                          float* __restrict__ outV) {
    int b = blockIdx.x;
    if (b >= *count) return;
    int i = heads[b];
    int s = idx[i];
    int tid = threadIdx.x;
    __shared__ float V[512];
    V[tid] = mv[(size_t)s * 512 + tid];
    V[tid + 256] = mv[(size_t)s * 512 + tid + 256];
    float k0 = mk[(size_t)s * 512 + tid], k1 = mk[(size_t)s * 512 + tid + 256];
    __syncthreads();
    while (i >= 0) {
        float a0 = G1[(size_t)i * 512 + tid], a1 = G1[(size_t)i * 512 + tid + 256];
        for (int c = 0; c < 512; c++) {
            float vc = V[c];
            a0 += vc * Wg[(size_t)(512 + c) * 512 + tid];
            a1 += vc * Wg[(size_t)(512 + c) * 512 + tid + 256];
        }
        float g0 = 1.f / (1.f + __expf(-a0));
        float g1 = 1.f / (1.f + __expf(-a1));
        __syncthreads(); // everyone finished reading V
        k0 = g0 * wk[(size_t)i * 512 + tid] + (1.f - g0) * k0;
        k1 = g1 * wk[(size_t)i * 512 + tid + 256] + (1.f - g1) * k1;
        V[tid] = g0 * wv[(size_t)i * 512 + tid] + (1.f - g0) * V[tid];
        V[tid + 256] = g1 * wv[(size_t)i * 512 + tid + 256] + (1.f - g1) * V[tid + 256];
        __syncthreads();
        i = nxt[i];
    }
    outK[(size_t)s * 512 + tid] = k0;
    outK[(size_t)s * 512 + tid + 256] = k1;
    outV[(size_t)s * 512 + tid] = V[tid];
    outV[(size_t)s * 512 + tid + 256] = V[tid + 256];
}

// ---------------------------------------------------------------------------
extern "C" void kernel_launch(void* const* d_in, const int* in_sizes, int n_in,
                              void* d_out, int out_size, void* d_ws, size_t ws_size,
                              hipStream_t stream) {
    const float* queries = (const float*)d_in[0]; // [4,1024,512]
    const float* wkeys   = (const float*)d_in[1]; // [1024,512]
    const float* wvals   = (const float*)d_in[2]; // [1024,512]
    const float* mkeys   = (const float*)d_in[3]; // [4096,512]
    const float* mvals   = (const float*)d_in[4]; // [4096,512]
    const float* Wq      = (const float*)d_in[5]; // [512,4096]
    const float* bq      = (const float*)d_in[6]; // [4096]
    const float* Wvp     = (const float*)d_in[7]; // [4096,512]
    const float* bvp     = (const float*)d_in[8]; // [512]
    const float* Wg      = (const float*)d_in[9]; // [1024,512]
    const float* bg      = (const float*)d_in[10];// [512]

    float* out_read = (float*)d_out;              // [4,1024,512]
    float* out_k = out_read + (size_t)4 * 1024 * 512; // [4096,512]
    float* out_v = out_k + (size_t)4096 * 512;        // [4096,512]

    char* ws = (char*)d_ws;
    const size_t MB = 1024 * 1024;
    // region [0, 4MB): Qbf during prep/q-proj, then reused for meta + denom
    u16* Qbf  = (u16*)(ws);            // 4 MB   queries bf16 [4096,512]
    u16* WqT  = (u16*)(ws + 4 * MB);   // 4 MB   Wq^T bf16 [4096,512]
    u16* Qatt = (u16*)(ws + 8 * MB);   // 32 MB  q bf16 [(b,h),n,d] = [32768,512]
    u16* Kb   = (u16*)(ws + 40 * MB);  // 4 MB   mem_keys bf16 [4096,512]
    u16* Vtb  = (u16*)(ws + 44 * MB);  // 4 MB   mem_values^T bf16 [512,4096]
    u16* rv   = (u16*)(ws + 48 * MB);  // 32 MB  attention out bf16 [4096,4096]
    u16* WvpT = (u16*)(ws + 80 * MB);  // 4 MB   Wvp^T bf16 [512,4096]
    float* mn  = (float*)(ws + 84 * MB); // 8 MB normalized mem_keys [4096,512]
    float* G1  = (float*)(ws + 92 * MB); // 2 MB gate pre from write_keys [1024,512]
    float* mnT = (float*)(ws + 94 * MB); // 8 MB normalized keys transposed [512,4096]
    // meta + denom overlay the dead Qbf region (valid after q-proj completes)
    u64* amax   = (u64*)(ws);                   // 8 KB
    int* count  = (int*)(ws + 8192);            // 4 B
    int* idx    = (int*)(ws + 8192 + 256);      // 4 KB
    int* nxt    = (int*)(ws + 8192 + 256 + 4096);   // 4 KB
    int* heads  = (int*)(ws + 8192 + 256 + 8192);   // 4 KB
    float* denom = (float*)(ws + 32 * 1024);    // 128 KB [32768]
    // P overlays the dead mn/G1/mnT region (valid after chain_apply completes)
    u16* P = (u16*)(ws + 84 * MB);              // up to 256 MB [G*1024, 4096]
    (void)in_sizes; (void)n_in; (void)out_size;

    // chunk size over bh: P needs G*8MB starting at 84MB
    size_t avail = (ws_size > 84 * MB) ? ws_size - 84 * MB : 0;
    int G = 2; // proven-safe floor: 16 MB fits in [84MB, 100MB) (ws >= 102MB)
    for (int g = 32; g >= 2; g >>= 1)
        if ((size_t)g * 8 * MB <= avail) { G = g; break; }

    // new_keys / new_values start as copies of mem_keys / mem_values
    hipMemcpyAsync(out_k, mkeys, (size_t)4096 * 512 * 4, hipMemcpyDeviceToDevice, stream);
    hipMemcpyAsync(out_v, mvals, (size_t)4096 * 512 * 4, hipMemcpyDeviceToDevice, stream);

    // ---- prep casts / transposes ----
    cast_bf16_kernel<<<2048, 256, 0, stream>>>(queries, Qbf);
    cast_transpose_kernel<<<dim3(4096 / 32, 512 / 32), 256, 0, stream>>>(Wq, WqT, 512, 4096);
    cast_transpose_kernel<<<dim3(512 / 32, 4096 / 32), 256, 0, stream>>>(Wvp, WvpT, 4096, 512);
    cast_transpose_kernel<<<dim3(512 / 32, 4096 / 32), 256, 0, stream>>>(mvals, Vtb, 4096, 512);
    key_prep_kernel<<<4096, 256, 0, stream>>>(mkeys, mn, Kb);
    transpose_f32_kernel<<<dim3(512 / 32, 4096 / 32), 256, 0, stream>>>(mn, mnT, 4096, 512);

    // ---- q-proj (last user of Qbf/WqT) ----
    gemm_bt_kernel<128, 1><<<dim3(32, 32), 256, 0, stream>>>(Qbf, WqT, bq, (void*)Qatt, 4096, 4096, 512);

    // ---- write path (fp32), frees mn/G1/mnT for the P overlay afterwards ----
    hipMemsetAsync(ws, 0, 8192 + 256, stream);          // amax + count (Qbf now dead)
    hipMemsetAsync(denom, 0, 32768 * 4, stream);        // denom
    sims_argmax_kernel<<<dim3(64, 8), 256, 0, stream>>>(wkeys, mnT, amax);
    chains_build_kernel<<<16, 64, 0, stream>>>(amax, idx, nxt, heads, count);
    g1_gemm_kernel<<<128, 256, 0, stream>>>(wkeys, Wg, bg, G1);
    chain_apply_kernel<<<1024, 256, 0, stream>>>(heads, count, idx, nxt, G1, Wg,
                                                 wkeys, wvals, mkeys, mvals, out_k, out_v);

    // ---- attention as two GEMM passes, chunked over bh ----
    for (int bh0 = 0; bh0 < 32; bh0 += G) {
        const u16* Achunk = Qatt + (size_t)bh0 * 1024 * 512;
        float* dchunk = denom + bh0 * 1024;
        s_exp_gemm_kernel<<<dim3(32, G * 8), 256, 0, stream>>>(Achunk, Kb, P, dchunk);
        pv_gemm_kernel<<<dim3(4, G * 8), 256, 0, stream>>>(P, Vtb, dchunk, rv, bh0);
    }

    // ---- out-proj ----
    gemm_bt_kernel<64, 0><<<dim3(8, 32), 256, 0, stream>>>(rv, WvpT, bvp, (void*)out_read, 4096, 512, 4096);
}

// Round 6
// 923.114 us; speedup vs baseline: 1.1955x; 1.1195x over previous
//
#include <hip/hip_runtime.h>
#include <cstdint>
#include <cstddef>

typedef __attribute__((ext_vector_type(8))) short short8;
typedef __attribute__((ext_vector_type(4))) float f32x4;
typedef unsigned short u16;
typedef unsigned int u32;
typedef unsigned long long u64;

__device__ __forceinline__ u16 f2bf(float f) {
    u32 u = __float_as_uint(f);
    u = (u + 0x7FFFu + ((u >> 16) & 1u)) >> 16;
    return (u16)u;
}
__device__ __forceinline__ float bf2f(u16 h) {
    u32 u = ((u32)h) << 16;
    return __uint_as_float(u);
}

// ---------------------------------------------------------------------------
// Elementwise cast fp32 -> bf16 (vectorized x4). n must be multiple of 4.
__global__ void cast_bf16_kernel(const float* __restrict__ src, u16* __restrict__ dst) {
    int i = blockIdx.x * 256 + threadIdx.x;
    float4 v = *((const float4*)src + i);
    ushort4 r;
    r.x = f2bf(v.x); r.y = f2bf(v.y); r.z = f2bf(v.z); r.w = f2bf(v.w);
    *((ushort4*)dst + i) = r;
}

// ---------------------------------------------------------------------------
// Split fp32 -> (hi, lo) bf16 pair: hi = bf16(x), lo = bf16(x - fp32(hi)).
__global__ void split_bf16_kernel(const float* __restrict__ src,
                                  u16* __restrict__ hi, u16* __restrict__ lo) {
    int i = blockIdx.x * 256 + threadIdx.x;
    float4 v = *((const float4*)src + i);
    ushort4 h, l;
    h.x = f2bf(v.x); l.x = f2bf(v.x - bf2f(h.x));
    h.y = f2bf(v.y); l.y = f2bf(v.y - bf2f(h.y));
    h.z = f2bf(v.z); l.z = f2bf(v.z - bf2f(h.z));
    h.w = f2bf(v.w); l.w = f2bf(v.w - bf2f(h.w));
    *((ushort4*)hi + i) = h;
    *((ushort4*)lo + i) = l;
}

// ---------------------------------------------------------------------------
// Tiled transpose: src fp32 [R][C] -> dst bf16 [C][R]. grid=(C/32, R/32), block=256.
__global__ void cast_transpose_kernel(const float* __restrict__ src, u16* __restrict__ dst,
                                      int R, int C) {
    __shared__ float tile[32][33];
    int tx = threadIdx.x & 31, ty = threadIdx.x >> 5;
    int c0 = blockIdx.x * 32, r0 = blockIdx.y * 32;
#pragma unroll
    for (int j = 0; j < 4; j++)
        tile[ty + 8 * j][tx] = src[(size_t)(r0 + ty + 8 * j) * C + c0 + tx];
    __syncthreads();
#pragma unroll
    for (int j = 0; j < 4; j++)
        dst[(size_t)(c0 + ty + 8 * j) * R + r0 + tx] = f2bf(tile[tx][ty + 8 * j]);
}

// ---------------------------------------------------------------------------
// mem_keys -> mn_hi/mn_lo (split-bf16 row-normalized, B^T layout for sims MFMA)
// and Kb (bf16 raw, for attention).
__global__ __launch_bounds__(256) void key_prep_kernel(const float* __restrict__ mk,
                                                       u16* __restrict__ mn_hi,
                                                       u16* __restrict__ mn_lo,
                                                       u16* __restrict__ Kb) {
    int row = blockIdx.x, tid = threadIdx.x;
    const float* src = mk + (size_t)row * 512;
    float x0 = src[tid], x1 = src[tid + 256];
    float ss = x0 * x0 + x1 * x1;
#pragma unroll
    for (int m = 1; m < 64; m <<= 1) ss += __shfl_xor(ss, m);
    __shared__ float sred[4];
    if ((tid & 63) == 0) sred[tid >> 6] = ss;
    __syncthreads();
    float tot = sred[0] + sred[1] + sred[2] + sred[3];
    float inv = 1.0f / fmaxf(sqrtf(tot), 1e-8f);
    float n0 = x0 * inv, n1 = x1 * inv;
    u16 h0 = f2bf(n0), h1 = f2bf(n1);
    mn_hi[(size_t)row * 512 + tid] = h0;
    mn_hi[(size_t)row * 512 + tid + 256] = h1;
    mn_lo[(size_t)row * 512 + tid] = f2bf(n0 - bf2f(h0));
    mn_lo[(size_t)row * 512 + tid + 256] = f2bf(n1 - bf2f(h1));
    Kb[(size_t)row * 512 + tid] = f2bf(x0);
    Kb[(size_t)row * 512 + tid + 256] = f2bf(x1);
}

// ---------------------------------------------------------------------------
// GEMM: C[M,N] = A[M,K] * Bt[N,K]^T + bias[N].  bf16 inputs, fp32 accumulate.
// BM=128 fixed, BN template (128 or 64). block=256 (4 waves, 2x2 quadrants).
// EPI==0: write fp32 C row-major [M,N].
// EPI==1: q-proj permute: row=(b*1024+n), col=(h*512+d) -> Qatt bf16 [((b*8+h)*1024+n)*512+d]
template <int BN, int EPI>
__global__ __launch_bounds__(256, 2) void gemm_bt_kernel(const u16* __restrict__ A,
                                                         const u16* __restrict__ Bt,
                                                         const float* __restrict__ bias,
                                                         void* __restrict__ Cout,
                                                         int M, int N, int K) {
    constexpr int NT = BN / 32;
    __shared__ __align__(16) u16 A_lds[128 * 40];
    __shared__ __align__(16) u16 B_lds[BN * 40];
    int tid = threadIdx.x;
    int w = tid >> 6, lane = tid & 63, l15 = lane & 15, quad = lane >> 4;
    int wm = w >> 1, wn = w & 1;
    int n0 = blockIdx.x * BN, m0 = blockIdx.y * 128;

    f32x4 acc[4][NT];
#pragma unroll
    for (int i = 0; i < 4; i++)
#pragma unroll
        for (int j = 0; j < NT; j++) acc[i][j] = (f32x4)(0.0f);

    for (int kt = 0; kt < K; kt += 32) {
        __syncthreads();
#pragma unroll
        for (int i = 0; i < 2; i++) {
            int c = i * 256 + tid;
            int r = c >> 2, col = c & 3;
            *(uint4*)&A_lds[r * 40 + col * 8] =
                *(const uint4*)&A[(size_t)(m0 + r) * K + kt + col * 8];
        }
#pragma unroll
        for (int i = 0; i < BN / 64; i++) {
            int c = i * 256 + tid;
            int r = c >> 2, col = c & 3;
            *(uint4*)&B_lds[r * 40 + col * 8] =
                *(const uint4*)&Bt[(size_t)(n0 + r) * K + kt + col * 8];
        }
        __syncthreads();
        short8 af[4], bf[NT];
#pragma unroll
        for (int mt = 0; mt < 4; mt++)
            af[mt] = *(const short8*)&A_lds[(wm * 64 + mt * 16 + l15) * 40 + quad * 8];
#pragma unroll
        for (int nt = 0; nt < NT; nt++)
            bf[nt] = *(const short8*)&B_lds[(wn * (BN / 2) + nt * 16 + l15) * 40 + quad * 8];
#pragma unroll
        for (int mt = 0; mt < 4; mt++)
#pragma unroll
            for (int nt = 0; nt < NT; nt++)
                acc[mt][nt] = __builtin_amdgcn_mfma_f32_16x16x32_bf16(af[mt], bf[nt], acc[mt][nt], 0, 0, 0);
    }

#pragma unroll
    for (int nt = 0; nt < NT; nt++) {
        int col = n0 + wn * (BN / 2) + nt * 16 + l15;
        float bs = bias[col];
#pragma unroll
        for (int mt = 0; mt < 4; mt++) {
            int row = m0 + wm * 64 + mt * 16 + quad * 4;
#pragma unroll
            for (int r = 0; r < 4; r++) {
                float v = acc[mt][nt][r] + bs;
                if (EPI == 0) {
                    ((float*)Cout)[(size_t)(row + r) * N + col] = v;
                } else {
                    int rr = row + r;
                    int bi = rr >> 10, ni = rr & 1023;
                    int h = col >> 9, d = col & 511;
                    ((u16*)Cout)[(((size_t)((bi * 8 + h)) * 1024 + ni)) * 512 + d] = f2bf(v);
                }
            }
        }
    }
}

// ---------------------------------------------------------------------------
// S-pass: P[M,4096] = exp2(sc * A[M,512] * Kb[4096,512]^T), denom[row] += rowsum.
// m97 structure: BM=128, BN=128, K=512. grid=(32, M/128). A/denom pre-offset by bh0.
__global__ __launch_bounds__(256, 2) void s_exp_gemm_kernel(const u16* __restrict__ A,
                                                            const u16* __restrict__ Bt,
                                                            u16* __restrict__ P,
                                                            float* __restrict__ denom) {
    __shared__ __align__(16) u16 A_lds[128 * 40];
    __shared__ __align__(16) u16 B_lds[128 * 40];
    int tid = threadIdx.x;
    int w = tid >> 6, lane = tid & 63, l15 = lane & 15, quad = lane >> 4;
    int wm = w >> 1, wn = w & 1;
    int n0 = blockIdx.x * 128, m0 = blockIdx.y * 128;

    f32x4 acc[4][4];
#pragma unroll
    for (int i = 0; i < 4; i++)
#pragma unroll
        for (int j = 0; j < 4; j++) acc[i][j] = (f32x4)(0.0f);

    for (int kt = 0; kt < 512; kt += 32) {
        __syncthreads();
#pragma unroll
        for (int i = 0; i < 2; i++) {
            int c = i * 256 + tid;
            int r = c >> 2, col = c & 3;
            *(uint4*)&A_lds[r * 40 + col * 8] =
                *(const uint4*)&A[(size_t)(m0 + r) * 512 + kt + col * 8];
            *(uint4*)&B_lds[r * 40 + col * 8] =
                *(const uint4*)&Bt[(size_t)(n0 + r) * 512 + kt + col * 8];
        }
        __syncthreads();
        short8 af[4], bf[4];
#pragma unroll
        for (int mt = 0; mt < 4; mt++)
            af[mt] = *(const short8*)&A_lds[(wm * 64 + mt * 16 + l15) * 40 + quad * 8];
#pragma unroll
        for (int nt = 0; nt < 4; nt++)
            bf[nt] = *(const short8*)&B_lds[(wn * 64 + nt * 16 + l15) * 40 + quad * 8];
#pragma unroll
        for (int mt = 0; mt < 4; mt++)
#pragma unroll
            for (int nt = 0; nt < 4; nt++)
                acc[mt][nt] = __builtin_amdgcn_mfma_f32_16x16x32_bf16(af[mt], bf[nt], acc[mt][nt], 0, 0, 0);
    }

    const float sc = 0.06375871826463886f; // log2(e)/sqrt(512)
#pragma unroll
    for (int mt = 0; mt < 4; mt++) {
#pragma unroll
        for (int r = 0; r < 4; r++) {
            int row = m0 + wm * 64 + mt * 16 + quad * 4 + r;
            float rs = 0.f;
#pragma unroll
            for (int nt = 0; nt < 4; nt++) {
                int col = n0 + wn * 64 + nt * 16 + l15;
                float p = exp2f(acc[mt][nt][r] * sc);
                rs += p;
                P[(size_t)row * 4096 + col] = f2bf(p);
            }
            rs += __shfl_xor(rs, 1); rs += __shfl_xor(rs, 2);
            rs += __shfl_xor(rs, 4); rs += __shfl_xor(rs, 8);
            if (l15 == 0) atomicAdd(&denom[row], rs);
        }
    }
}

// ---------------------------------------------------------------------------
// PV-pass: rv = (P[M,4096] * Vtb[512,4096]^T) / denom, scattered to
// rv[b*1024+n, h*512+d] with global row gr = bh0*1024 + local row.
// BM=128, BN=128, K=4096. grid=(4, M/128). P/denom pre-offset by bh0.
__global__ __launch_bounds__(256, 2) void pv_gemm_kernel(const u16* __restrict__ A,
                                                         const u16* __restrict__ Bt,
                                                         const float* __restrict__ denom,
                                                         u16* __restrict__ rv,
                                                         int bh0) {
    __shared__ __align__(16) u16 A_lds[128 * 40];
    __shared__ __align__(16) u16 B_lds[128 * 40];
    int tid = threadIdx.x;
    int w = tid >> 6, lane = tid & 63, l15 = lane & 15, quad = lane >> 4;
    int wm = w >> 1, wn = w & 1;
    int n0 = blockIdx.x * 128, m0 = blockIdx.y * 128;

    f32x4 acc[4][4];
#pragma unroll
    for (int i = 0; i < 4; i++)
#pragma unroll
        for (int j = 0; j < 4; j++) acc[i][j] = (f32x4)(0.0f);

    for (int kt = 0; kt < 4096; kt += 32) {
        __syncthreads();
#pragma unroll
        for (int i = 0; i < 2; i++) {
            int c = i * 256 + tid;
            int r = c >> 2, col = c & 3;
            *(uint4*)&A_lds[r * 40 + col * 8] =
                *(const uint4*)&A[(size_t)(m0 + r) * 4096 + kt + col * 8];
            *(uint4*)&B_lds[r * 40 + col * 8] =
                *(const uint4*)&Bt[(size_t)(n0 + r) * 4096 + kt + col * 8];
        }
        __syncthreads();
        short8 af[4], bf[4];
#pragma unroll
        for (int mt = 0; mt < 4; mt++)
            af[mt] = *(const short8*)&A_lds[(wm * 64 + mt * 16 + l15) * 40 + quad * 8];
#pragma unroll
        for (int nt = 0; nt < 4; nt++)
            bf[nt] = *(const short8*)&B_lds[(wn * 64 + nt * 16 + l15) * 40 + quad * 8];
#pragma unroll
        for (int mt = 0; mt < 4; mt++)
#pragma unroll
            for (int nt = 0; nt < 4; nt++)
                acc[mt][nt] = __builtin_amdgcn_mfma_f32_16x16x32_bf16(af[mt], bf[nt], acc[mt][nt], 0, 0, 0);
    }

#pragma unroll
    for (int mt = 0; mt < 4; mt++) {
#pragma unroll
        for (int r = 0; r < 4; r++) {
            int lr = m0 + wm * 64 + mt * 16 + quad * 4 + r;
            int gr = bh0 * 1024 + lr;
            float inv = 1.0f / denom[lr];
            int b = gr >> 13, h = (gr >> 10) & 7, n = gr & 1023;
            size_t base = ((size_t)(b * 1024 + n)) * 4096 + h * 512;
#pragma unroll
            for (int nt = 0; nt < 4; nt++) {
                int col = n0 + wn * 64 + nt * 16 + l15;
                rv[base + col] = f2bf(acc[mt][nt][r] * inv);
            }
        }
    }
}

// ---------------------------------------------------------------------------
// sims v3: MFMA GEMM with split-bf16 precision (plain bf16 would misrank:
// dot noise sigma~4e-3 vs top-2 gap ~0.28 sigma -> ~14 bad rows/1024).
// sims[wi][m] = wk[wi]. mn[m] ~ wh.mh + wh.ml + wl.mh (lo*lo dropped, ~4e-6).
// A = wk hi/lo [1024,512] (raw: row scale is argmax-invariant),
// Bt = mn hi/lo [4096,512]. grid=(4096/128, 1024/128)=(32,8). Epilogue:
// per-row argmax keys (ties -> smaller m), atomicMax into amax.
__global__ __launch_bounds__(256, 2) void sims_mfma_kernel(const u16* __restrict__ Ah,
                                                           const u16* __restrict__ Al,
                                                           const u16* __restrict__ Bh,
                                                           const u16* __restrict__ Bl,
                                                           u64* __restrict__ amax) {
    __shared__ __align__(16) u16 Ah_lds[128 * 40];
    __shared__ __align__(16) u16 Al_lds[128 * 40];
    __shared__ __align__(16) u16 Bh_lds[128 * 40];
    __shared__ __align__(16) u16 Bl_lds[128 * 40];
    int tid = threadIdx.x;
    int w = tid >> 6, lane = tid & 63, l15 = lane & 15, quad = lane >> 4;
    int wm = w >> 1, wn = w & 1;
    int n0 = blockIdx.x * 128, m0 = blockIdx.y * 128;

    f32x4 acc[4][4];
#pragma unroll
    for (int i = 0; i < 4; i++)
#pragma unroll
        for (int j = 0; j < 4; j++) acc[i][j] = (f32x4)(0.0f);

    for (int kt = 0; kt < 512; kt += 32) {
        __syncthreads();
#pragma unroll
        for (int i = 0; i < 2; i++) {
            int c = i * 256 + tid;
            int r = c >> 2, col = c & 3;
            size_t ga = (size_t)(m0 + r) * 512 + kt + col * 8;
            size_t gb = (size_t)(n0 + r) * 512 + kt + col * 8;
            *(uint4*)&Ah_lds[r * 40 + col * 8] = *(const uint4*)&Ah[ga];
            *(uint4*)&Al_lds[r * 40 + col * 8] = *(const uint4*)&Al[ga];
            *(uint4*)&Bh_lds[r * 40 + col * 8] = *(const uint4*)&Bh[gb];
            *(uint4*)&Bl_lds[r * 40 + col * 8] = *(const uint4*)&Bl[gb];
        }
        __syncthreads();
        short8 afh[4], afl[4], bfh[4], bfl[4];
#pragma unroll
        for (int mt = 0; mt < 4; mt++) {
            int off = (wm * 64 + mt * 16 + l15) * 40 + quad * 8;
            afh[mt] = *(const short8*)&Ah_lds[off];
            afl[mt] = *(const short8*)&Al_lds[off];
        }
#pragma unroll
        for (int nt = 0; nt < 4; nt++) {
            int off = (wn * 64 + nt * 16 + l15) * 40 + quad * 8;
            bfh[nt] = *(const short8*)&Bh_lds[off];
            bfl[nt] = *(const short8*)&Bl_lds[off];
        }
#pragma unroll
        for (int mt = 0; mt < 4; mt++)
#pragma unroll
            for (int nt = 0; nt < 4; nt++) {
                acc[mt][nt] = __builtin_amdgcn_mfma_f32_16x16x32_bf16(afh[mt], bfh[nt], acc[mt][nt], 0, 0, 0);
                acc[mt][nt] = __builtin_amdgcn_mfma_f32_16x16x32_bf16(afh[mt], bfl[nt], acc[mt][nt], 0, 0, 0);
                acc[mt][nt] = __builtin_amdgcn_mfma_f32_16x16x32_bf16(afl[mt], bfh[nt], acc[mt][nt], 0, 0, 0);
            }
    }

#pragma unroll
    for (int mt = 0; mt < 4; mt++) {
#pragma unroll
        for (int r = 0; r < 4; r++) {
            int row = m0 + wm * 64 + mt * 16 + quad * 4 + r;  // wi index
            u64 best = 0;
#pragma unroll
            for (int nt = 0; nt < 4; nt++) {
                int col = n0 + wn * 64 + nt * 16 + l15;       // slot index
                u32 bb = __float_as_uint(acc[mt][nt][r]);
                bb = (bb & 0x80000000u) ? ~bb : (bb | 0x80000000u);
                u64 key = ((u64)bb << 32) | (u32)(4095 - col);
                best = best > key ? best : key;
            }
            // reduce over the 16 l15 lanes (stays within the quad's lane group)
            u64 o;
            o = __shfl_xor(best, 1); best = best > o ? best : o;
            o = __shfl_xor(best, 2); best = best > o ? best : o;
            o = __shfl_xor(best, 4); best = best > o ? best : o;
            o = __shfl_xor(best, 8); best = best > o ? best : o;
            if (l15 == 0) atomicMax(&amax[row], best);
        }
    }
}

// ---------------------------------------------------------------------------
// chains_build v2: decode idx, build per-slot chains. 16 blocks x 64 threads;
// every block mirrors all 1024 decoded indices in LDS, wave b handles
// i in [64b, 64b+64). Scans are LDS reads instead of global pointer-chases.
__global__ __launch_bounds__(64) void chains_build_kernel(const u64* __restrict__ amax,
                                                          int* __restrict__ idx,
                                                          int* __restrict__ nxt,
                                                          int* __restrict__ heads,
                                                          int* __restrict__ count) {
    __shared__ int sidx[1024];
    int tid = threadIdx.x;
    for (int j = tid; j < 1024; j += 64)
        sidx[j] = 4095 - (int)(u32)(amax[j] & 0xFFFFFFFFull);
    __syncthreads();
    int i = blockIdx.x * 64 + tid;
    int my = sidx[i];
    idx[i] = my;
    int nx = -1;
    for (int j = i + 1; j < 1024; j++)
        if (sidx[j] == my) { nx = j; break; }
    nxt[i] = nx;
    bool head = true;
    for (int j = 0; j < i; j++)
        if (sidx[j] == my) { head = false; break; }
    if (head) {
        int p = atomicAdd(count, 1);
        heads[p] = i;
    }
}

// ---------------------------------------------------------------------------
// G1[i][j] = write_keys[i] . Wg[0:512, j] + bg[j]   (fp32). 8 rows/block, grid=128.
__global__ __launch_bounds__(256) void g1_gemm_kernel(const float* __restrict__ wk,
                                                      const float* __restrict__ Wg,
                                                      const float* __restrict__ bg,
                                                      float* __restrict__ G1) {
    __shared__ float wkl[8][512];
    int tid = threadIdx.x;
    int i0 = blockIdx.x * 8;
    for (int i = tid; i < 8 * 512; i += 256) wkl[i >> 9][i & 511] = wk[(size_t)i0 * 512 + i];
    __syncthreads();
    float a0[8], a1[8];
#pragma unroll
    for (int i = 0; i < 8; i++) { a0[i] = 0.f; a1[i] = 0.f; }
    for (int c = 0; c < 512; c++) {
        float w0 = Wg[(size_t)c * 512 + tid];
        float w1 = Wg[(size_t)c * 512 + tid + 256];
#pragma unroll
        for (int ii = 0; ii < 8; ii++) {
            float s = wkl[ii][c];
            a0[ii] += s * w0; a1[ii] += s * w1;
        }
    }
    float b0 = bg[tid], b1 = bg[tid + 256];
#pragma unroll
    for (int ii = 0; ii < 8; ii++) {
        G1[(size_t)(i0 + ii) * 512 + tid] = a0[ii] + b0;
        G1[(size_t)(i0 + ii) * 512 + tid + 256] = a1[ii] + b1;
    }
}

// ---------------------------------------------------------------------------
// Apply per-slot chains sequentially (fp32). block = 256 threads per chain.
__global__ __launch_bounds__(256) void chain_apply_kernel(const int* __restrict__ heads,
                                                          const int* __restrict__ count,
                                                          const int* __restrict__ idx,
                                                          const int* __restrict__ nxt,
                                                          const float* __restrict__ G1,
                                                          const float* __restrict__ Wg,
                                                          const float* __restrict__ wk,
                                                          const float* __restrict__ wv,
                                                          const float* __restrict__ mk,
                                                          const float* __restrict__ mv,
                                                          float* __restrict__ outK,
                                                          float* __restrict__ outV) {
    int b = blockIdx.x;
    if (b >= *count) return;
    int i = heads[b];
    int s = idx[i];
    int tid = threadIdx.x;
    __shared__ float V[512];
    V[tid] = mv[(size_t)s * 512 + tid];
    V[tid + 256] = mv[(size_t)s * 512 + tid + 256];
    float k0 = mk[(size_t)s * 512 + tid], k1 = mk[(size_t)s * 512 + tid + 256];
    __syncthreads();
    while (i >= 0) {
        float a0 = G1[(size_t)i * 512 + tid], a1 = G1[(size_t)i * 512 + tid + 256];
        for (int c = 0; c < 512; c++) {
            float vc = V[c];
            a0 += vc * Wg[(size_t)(512 + c) * 512 + tid];
            a1 += vc * Wg[(size_t)(512 + c) * 512 + tid + 256];
        }
        float g0 = 1.f / (1.f + __expf(-a0));
        float g1 = 1.f / (1.f + __expf(-a1));
        __syncthreads(); // everyone finished reading V
        k0 = g0 * wk[(size_t)i * 512 + tid] + (1.f - g0) * k0;
        k1 = g1 * wk[(size_t)i * 512 + tid + 256] + (1.f - g1) * k1;
        V[tid] = g0 * wv[(size_t)i * 512 + tid] + (1.f - g0) * V[tid];
        V[tid + 256] = g1 * wv[(size_t)i * 512 + tid + 256] + (1.f - g1) * V[tid + 256];
        __syncthreads();
        i = nxt[i];
    }
    outK[(size_t)s * 512 + tid] = k0;
    outK[(size_t)s * 512 + tid + 256] = k1;
    outV[(size_t)s * 512 + tid] = V[tid];
    outV[(size_t)s * 512 + tid + 256] = V[tid + 256];
}

// ---------------------------------------------------------------------------
extern "C" void kernel_launch(void* const* d_in, const int* in_sizes, int n_in,
                              void* d_out, int out_size, void* d_ws, size_t ws_size,
                              hipStream_t stream) {
    const float* queries = (const float*)d_in[0]; // [4,1024,512]
    const float* wkeys   = (const float*)d_in[1]; // [1024,512]
    const float* wvals   = (const float*)d_in[2]; // [1024,512]
    const float* mkeys   = (const float*)d_in[3]; // [4096,512]
    const float* mvals   = (const float*)d_in[4]; // [4096,512]
    const float* Wq      = (const float*)d_in[5]; // [512,4096]
    const float* bq      = (const float*)d_in[6]; // [4096]
    const float* Wvp     = (const float*)d_in[7]; // [4096,512]
    const float* bvp     = (const float*)d_in[8]; // [512]
    const float* Wg      = (const float*)d_in[9]; // [1024,512]
    const float* bg      = (const float*)d_in[10];// [512]

    float* out_read = (float*)d_out;              // [4,1024,512]
    float* out_k = out_read + (size_t)4 * 1024 * 512; // [4096,512]
    float* out_v = out_k + (size_t)4096 * 512;        // [4096,512]

    char* ws = (char*)d_ws;
    const size_t MB = 1024 * 1024;
    // region [0, 4MB): Qbf during prep/q-proj, then reused for meta + denom
    u16* Qbf  = (u16*)(ws);            // 4 MB   queries bf16 [4096,512]
    u16* WqT  = (u16*)(ws + 4 * MB);   // 4 MB   Wq^T bf16 [4096,512]
    u16* Qatt = (u16*)(ws + 8 * MB);   // 32 MB  q bf16 [(b,h),n,d] = [32768,512]
    u16* Kb   = (u16*)(ws + 40 * MB);  // 4 MB   mem_keys bf16 [4096,512]
    u16* Vtb  = (u16*)(ws + 44 * MB);  // 4 MB   mem_values^T bf16 [512,4096]
    u16* rv   = (u16*)(ws + 48 * MB);  // 32 MB  attention out bf16 [4096,4096]
    u16* WvpT = (u16*)(ws + 80 * MB);  // 4 MB   Wvp^T bf16 [512,4096]
    // write-path buffers (dead before attention's P overlay):
    u16* mn_hi = (u16*)(ws + 84 * MB); // 4 MB  normalized keys hi bf16 [4096,512]
    u16* mn_lo = (u16*)(ws + 88 * MB); // 4 MB  normalized keys lo bf16 [4096,512]
    float* G1  = (float*)(ws + 92 * MB); // 2 MB gate pre from write_keys [1024,512]
    u16* wk_hi = (u16*)(ws + 94 * MB); // 1 MB  write_keys hi bf16 [1024,512]
    u16* wk_lo = (u16*)(ws + 95 * MB); // 1 MB  write_keys lo bf16 [1024,512]
    // meta + denom overlay the dead Qbf region (valid after q-proj completes)
    u64* amax   = (u64*)(ws);                   // 8 KB
    int* count  = (int*)(ws + 8192);            // 4 B
    int* idx    = (int*)(ws + 8192 + 256);      // 4 KB
    int* nxt    = (int*)(ws + 8192 + 256 + 4096);   // 4 KB
    int* heads  = (int*)(ws + 8192 + 256 + 8192);   // 4 KB
    float* denom = (float*)(ws + 32 * 1024);    // 128 KB [32768]
    // P overlays the dead write-path region (valid after chain_apply completes)
    u16* P = (u16*)(ws + 84 * MB);              // up to 256 MB [G*1024, 4096]
    (void)in_sizes; (void)n_in; (void)out_size;

    // chunk size over bh: P needs G*8MB starting at 84MB
    size_t avail = (ws_size > 84 * MB) ? ws_size - 84 * MB : 0;
    int G = 2; // proven-safe floor
    for (int g = 32; g >= 2; g >>= 1)
        if ((size_t)g * 8 * MB <= avail) { G = g; break; }

    // new_keys / new_values start as copies of mem_keys / mem_values
    hipMemcpyAsync(out_k, mkeys, (size_t)4096 * 512 * 4, hipMemcpyDeviceToDevice, stream);
    hipMemcpyAsync(out_v, mvals, (size_t)4096 * 512 * 4, hipMemcpyDeviceToDevice, stream);

    // ---- prep casts / transposes ----
    cast_bf16_kernel<<<2048, 256, 0, stream>>>(queries, Qbf);
    cast_transpose_kernel<<<dim3(4096 / 32, 512 / 32), 256, 0, stream>>>(Wq, WqT, 512, 4096);
    cast_transpose_kernel<<<dim3(512 / 32, 4096 / 32), 256, 0, stream>>>(Wvp, WvpT, 4096, 512);
    cast_transpose_kernel<<<dim3(512 / 32, 4096 / 32), 256, 0, stream>>>(mvals, Vtb, 4096, 512);
    key_prep_kernel<<<4096, 256, 0, stream>>>(mkeys, mn_hi, mn_lo, Kb);
    split_bf16_kernel<<<512, 256, 0, stream>>>(wkeys, wk_hi, wk_lo);

    // ---- q-proj (last user of Qbf/WqT) ----
    gemm_bt_kernel<128, 1><<<dim3(32, 32), 256, 0, stream>>>(Qbf, WqT, bq, (void*)Qatt, 4096, 4096, 512);

    // ---- write path (fp32-accurate), frees buffers for the P overlay after ----
    hipMemsetAsync(ws, 0, 8192 + 256, stream);          // amax + count (Qbf now dead)
    hipMemsetAsync(denom, 0, 32768 * 4, stream);        // denom
    sims_mfma_kernel<<<dim3(32, 8), 256, 0, stream>>>(wk_hi, wk_lo, mn_hi, mn_lo, amax);
    chains_build_kernel<<<16, 64, 0, stream>>>(amax, idx, nxt, heads, count);
    g1_gemm_kernel<<<128, 256, 0, stream>>>(wkeys, Wg, bg, G1);
    chain_apply_kernel<<<1024, 256, 0, stream>>>(heads, count, idx, nxt, G1, Wg,
                                                 wkeys, wvals, mkeys, mvals, out_k, out_v);

    // ---- attention as two GEMM passes, chunked over bh ----
    for (int bh0 = 0; bh0 < 32; bh0 += G) {
        const u16* Achunk = Qatt + (size_t)bh0 * 1024 * 512;
        float* dchunk = denom + bh0 * 1024;
        s_exp_gemm_kernel<<<dim3(32, G * 8), 256, 0, stream>>>(Achunk, Kb, P, dchunk);
        pv_gemm_kernel<<<dim3(4, G * 8), 256, 0, stream>>>(P, Vtb, dchunk, rv, bh0);
    }

    // ---- out-proj ----
    gemm_bt_kernel<64, 0><<<dim3(8, 32), 256, 0, stream>>>(rv, WvpT, bvp, (void*)out_read, 4096, 512, 4096);
}

// Round 7
// 828.741 us; speedup vs baseline: 1.3317x; 1.1139x over previous
//
#include <hip/hip_runtime.h>
#include <cstdint>
#include <cstddef>

typedef __attribute__((ext_vector_type(8))) short short8;
typedef __attribute__((ext_vector_type(4))) float f32x4;
typedef unsigned char u8;
typedef unsigned short u16;
typedef unsigned int u32;
typedef unsigned long long u64;

__device__ __forceinline__ u16 f2bf(float f) {
    u32 u = __float_as_uint(f);
    u = (u + 0x7FFFu + ((u >> 16) & 1u)) >> 16;
    return (u16)u;
}
__device__ __forceinline__ float bf2f(u16 h) {
    u32 u = ((u32)h) << 16;
    return __uint_as_float(u);
}
__device__ __forceinline__ u8 f2fp8(float f) {
    return (u8)(__builtin_amdgcn_cvt_pk_fp8_f32(f, f, 0, false) & 0xFF);
}

// ---------------------------------------------------------------------------
// Elementwise cast fp32 -> bf16 (vectorized x4). n must be multiple of 4.
__global__ void cast_bf16_kernel(const float* __restrict__ src, u16* __restrict__ dst) {
    int i = blockIdx.x * 256 + threadIdx.x;
    float4 v = *((const float4*)src + i);
    ushort4 r;
    r.x = f2bf(v.x); r.y = f2bf(v.y); r.z = f2bf(v.z); r.w = f2bf(v.w);
    *((ushort4*)dst + i) = r;
}

// ---------------------------------------------------------------------------
// Split fp32 -> (hi, lo) bf16 pair: hi = bf16(x), lo = bf16(x - fp32(hi)).
__global__ void split_bf16_kernel(const float* __restrict__ src,
                                  u16* __restrict__ hi, u16* __restrict__ lo) {
    int i = blockIdx.x * 256 + threadIdx.x;
    float4 v = *((const float4*)src + i);
    ushort4 h, l;
    h.x = f2bf(v.x); l.x = f2bf(v.x - bf2f(h.x));
    h.y = f2bf(v.y); l.y = f2bf(v.y - bf2f(h.y));
    h.z = f2bf(v.z); l.z = f2bf(v.z - bf2f(h.z));
    h.w = f2bf(v.w); l.w = f2bf(v.w - bf2f(h.w));
    *((ushort4*)hi + i) = h;
    *((ushort4*)lo + i) = l;
}

// ---------------------------------------------------------------------------
// Tiled transpose: src fp32 [R][C] -> dst bf16 [C][R]. grid=(C/32, R/32), block=256.
__global__ void cast_transpose_kernel(const float* __restrict__ src, u16* __restrict__ dst,
                                      int R, int C) {
    __shared__ float tile[32][33];
    int tx = threadIdx.x & 31, ty = threadIdx.x >> 5;
    int c0 = blockIdx.x * 32, r0 = blockIdx.y * 32;
#pragma unroll
    for (int j = 0; j < 4; j++)
        tile[ty + 8 * j][tx] = src[(size_t)(r0 + ty + 8 * j) * C + c0 + tx];
    __syncthreads();
#pragma unroll
    for (int j = 0; j < 4; j++)
        dst[(size_t)(c0 + ty + 8 * j) * R + r0 + tx] = f2bf(tile[tx][ty + 8 * j]);
}

// Tiled transpose: src fp32 [R][C] -> dst fp8 e4m3 [C][R]. (for V^T in PV pass)
__global__ void cast_transpose_fp8_kernel(const float* __restrict__ src, u8* __restrict__ dst,
                                          int R, int C) {
    __shared__ float tile[32][33];
    int tx = threadIdx.x & 31, ty = threadIdx.x >> 5;
    int c0 = blockIdx.x * 32, r0 = blockIdx.y * 32;
#pragma unroll
    for (int j = 0; j < 4; j++)
        tile[ty + 8 * j][tx] = src[(size_t)(r0 + ty + 8 * j) * C + c0 + tx];
    __syncthreads();
#pragma unroll
    for (int j = 0; j < 4; j++)
        dst[(size_t)(c0 + ty + 8 * j) * R + r0 + tx] = f2fp8(tile[tx][ty + 8 * j]);
}

// ---------------------------------------------------------------------------
// mem_keys -> mn_hi/mn_lo (split-bf16 row-normalized, B^T layout for sims MFMA)
// and Kb (bf16 raw, for attention).
__global__ __launch_bounds__(256) void key_prep_kernel(const float* __restrict__ mk,
                                                       u16* __restrict__ mn_hi,
                                                       u16* __restrict__ mn_lo,
                                                       u16* __restrict__ Kb) {
    int row = blockIdx.x, tid = threadIdx.x;
    const float* src = mk + (size_t)row * 512;
    float x0 = src[tid], x1 = src[tid + 256];
    float ss = x0 * x0 + x1 * x1;
#pragma unroll
    for (int m = 1; m < 64; m <<= 1) ss += __shfl_xor(ss, m);
    __shared__ float sred[4];
    if ((tid & 63) == 0) sred[tid >> 6] = ss;
    __syncthreads();
    float tot = sred[0] + sred[1] + sred[2] + sred[3];
    float inv = 1.0f / fmaxf(sqrtf(tot), 1e-8f);
    float n0 = x0 * inv, n1 = x1 * inv;
    u16 h0 = f2bf(n0), h1 = f2bf(n1);
    mn_hi[(size_t)row * 512 + tid] = h0;
    mn_hi[(size_t)row * 512 + tid + 256] = h1;
    mn_lo[(size_t)row * 512 + tid] = f2bf(n0 - bf2f(h0));
    mn_lo[(size_t)row * 512 + tid + 256] = f2bf(n1 - bf2f(h1));
    Kb[(size_t)row * 512 + tid] = f2bf(x0);
    Kb[(size_t)row * 512 + tid + 256] = f2bf(x1);
}

// ---------------------------------------------------------------------------
// GEMM: C[M,N] = A[M,K] * Bt[N,K]^T + bias[N].  bf16 inputs, fp32 accumulate.
// BM=128 fixed, BN template (128 or 64). block=256 (4 waves, 2x2 quadrants).
// EPI==0: write fp32 C row-major [M,N].
// EPI==1: q-proj permute: row=(b*1024+n), col=(h*512+d) -> Qatt bf16 [((b*8+h)*1024+n)*512+d]
template <int BN, int EPI>
__global__ __launch_bounds__(256, 2) void gemm_bt_kernel(const u16* __restrict__ A,
                                                         const u16* __restrict__ Bt,
                                                         const float* __restrict__ bias,
                                                         void* __restrict__ Cout,
                                                         int M, int N, int K) {
    constexpr int NT = BN / 32;
    __shared__ __align__(16) u16 A_lds[128 * 40];
    __shared__ __align__(16) u16 B_lds[BN * 40];
    int tid = threadIdx.x;
    int w = tid >> 6, lane = tid & 63, l15 = lane & 15, quad = lane >> 4;
    int wm = w >> 1, wn = w & 1;
    int n0 = blockIdx.x * BN, m0 = blockIdx.y * 128;

    f32x4 acc[4][NT];
#pragma unroll
    for (int i = 0; i < 4; i++)
#pragma unroll
        for (int j = 0; j < NT; j++) acc[i][j] = (f32x4)(0.0f);

    for (int kt = 0; kt < K; kt += 32) {
        __syncthreads();
#pragma unroll
        for (int i = 0; i < 2; i++) {
            int c = i * 256 + tid;
            int r = c >> 2, col = c & 3;
            *(uint4*)&A_lds[r * 40 + col * 8] =
                *(const uint4*)&A[(size_t)(m0 + r) * K + kt + col * 8];
        }
#pragma unroll
        for (int i = 0; i < BN / 64; i++) {
            int c = i * 256 + tid;
            int r = c >> 2, col = c & 3;
            *(uint4*)&B_lds[r * 40 + col * 8] =
                *(const uint4*)&Bt[(size_t)(n0 + r) * K + kt + col * 8];
        }
        __syncthreads();
        short8 af[4], bf[NT];
#pragma unroll
        for (int mt = 0; mt < 4; mt++)
            af[mt] = *(const short8*)&A_lds[(wm * 64 + mt * 16 + l15) * 40 + quad * 8];
#pragma unroll
        for (int nt = 0; nt < NT; nt++)
            bf[nt] = *(const short8*)&B_lds[(wn * (BN / 2) + nt * 16 + l15) * 40 + quad * 8];
#pragma unroll
        for (int mt = 0; mt < 4; mt++)
#pragma unroll
            for (int nt = 0; nt < NT; nt++)
                acc[mt][nt] = __builtin_amdgcn_mfma_f32_16x16x32_bf16(af[mt], bf[nt], acc[mt][nt], 0, 0, 0);
    }

#pragma unroll
    for (int nt = 0; nt < NT; nt++) {
        int col = n0 + wn * (BN / 2) + nt * 16 + l15;
        float bs = bias[col];
#pragma unroll
        for (int mt = 0; mt < 4; mt++) {
            int row = m0 + wm * 64 + mt * 16 + quad * 4;
#pragma unroll
            for (int r = 0; r < 4; r++) {
                float v = acc[mt][nt][r] + bs;
                if (EPI == 0) {
                    ((float*)Cout)[(size_t)(row + r) * N + col] = v;
                } else {
                    int rr = row + r;
                    int bi = rr >> 10, ni = rr & 1023;
                    int h = col >> 9, d = col & 511;
                    ((u16*)Cout)[(((size_t)((bi * 8 + h)) * 1024 + ni)) * 512 + d] = f2bf(v);
                }
            }
        }
    }
}

// ---------------------------------------------------------------------------
// S-pass: P[M,4096](fp8 e4m3) = exp2(sc * A[M,512] * Kb[4096,512]^T),
// denom[row] += rowsum (fp32, from unquantized p). BM=BN=128, K=512.
// grid=(32, M/128). Epilogue packs 4 cols -> 1 dword via 2 shfl rounds +
// cvt_pk_fp8 (replaces 64 scalar 2B stores + 64 f2bf sequences).
__global__ __launch_bounds__(256, 2) void s_exp_gemm_kernel(const u16* __restrict__ A,
                                                            const u16* __restrict__ Bt,
                                                            u8* __restrict__ P,
                                                            float* __restrict__ denom) {
    __shared__ __align__(16) u16 A_lds[128 * 40];
    __shared__ __align__(16) u16 B_lds[128 * 40];
    int tid = threadIdx.x;
    int w = tid >> 6, lane = tid & 63, l15 = lane & 15, quad = lane >> 4;
    int wm = w >> 1, wn = w & 1;
    int n0 = blockIdx.x * 128, m0 = blockIdx.y * 128;

    f32x4 acc[4][4];
#pragma unroll
    for (int i = 0; i < 4; i++)
#pragma unroll
        for (int j = 0; j < 4; j++) acc[i][j] = (f32x4)(0.0f);

    for (int kt = 0; kt < 512; kt += 32) {
        __syncthreads();
#pragma unroll
        for (int i = 0; i < 2; i++) {
            int c = i * 256 + tid;
            int r = c >> 2, col = c & 3;
            *(uint4*)&A_lds[r * 40 + col * 8] =
                *(const uint4*)&A[(size_t)(m0 + r) * 512 + kt + col * 8];
            *(uint4*)&B_lds[r * 40 + col * 8] =
                *(const uint4*)&Bt[(size_t)(n0 + r) * 512 + kt + col * 8];
        }
        __syncthreads();
        short8 af[4], bf[4];
#pragma unroll
        for (int mt = 0; mt < 4; mt++)
            af[mt] = *(const short8*)&A_lds[(wm * 64 + mt * 16 + l15) * 40 + quad * 8];
#pragma unroll
        for (int nt = 0; nt < 4; nt++)
            bf[nt] = *(const short8*)&B_lds[(wn * 64 + nt * 16 + l15) * 40 + quad * 8];
#pragma unroll
        for (int mt = 0; mt < 4; mt++)
#pragma unroll
            for (int nt = 0; nt < 4; nt++)
                acc[mt][nt] = __builtin_amdgcn_mfma_f32_16x16x32_bf16(af[mt], bf[nt], acc[mt][nt], 0, 0, 0);
    }

    const float sc = 0.06375871826463886f; // log2(e)/sqrt(512)
#pragma unroll
    for (int mt = 0; mt < 4; mt++) {
#pragma unroll
        for (int r = 0; r < 4; r++) {
            int row = m0 + wm * 64 + mt * 16 + quad * 4 + r;
            float rs = 0.f;
#pragma unroll
            for (int nt = 0; nt < 4; nt++) {
                float p = exp2f(acc[mt][nt][r] * sc);
                rs += p;
                // pack 4 adjacent cols (held by 4 adjacent l15 lanes) into 1 dword
                float pnb = __shfl_xor(p, 1);
                float plo = (l15 & 1) ? pnb : p;
                float phi = (l15 & 1) ? p : pnb;
                u32 pk2 = (u32)__builtin_amdgcn_cvt_pk_fp8_f32(plo, phi, 0, false) & 0xFFFFu;
                u32 oth = __shfl_xor(pk2, 2);
                u32 dw = (l15 & 2) ? (oth | (pk2 << 16)) : (pk2 | (oth << 16));
                if ((l15 & 3) == 0) {
                    int col = n0 + wn * 64 + nt * 16 + l15;
                    *(u32*)&P[(size_t)row * 4096 + col] = dw;
                }
            }
            rs += __shfl_xor(rs, 1); rs += __shfl_xor(rs, 2);
            rs += __shfl_xor(rs, 4); rs += __shfl_xor(rs, 8);
            if (l15 == 0) atomicAdd(&denom[row], rs);
        }
    }
}

// ---------------------------------------------------------------------------
// PV-pass (fp8): rv = (P[M,4096] * Vt8[512,4096]^T) / denom, bf16 out scattered
// to rv[b*1024+n, h*512+d]. A=P fp8, B=Vt8 fp8, mfma 16x16x32_fp8_fp8, BK=64.
// grid=(M/128, 4) with m on x (consecutive blocks share the 0.5MB B-tile -> L2).
__global__ __launch_bounds__(256, 2) void pv_gemm_kernel(const u8* __restrict__ A,
                                                         const u8* __restrict__ Bt,
                                                         const float* __restrict__ denom,
                                                         u16* __restrict__ rv,
                                                         int bh0) {
    __shared__ __align__(16) u8 A_lds[128 * 72];
    __shared__ __align__(16) u8 B_lds[128 * 72];
    int tid = threadIdx.x;
    int w = tid >> 6, lane = tid & 63, l15 = lane & 15, quad = lane >> 4;
    int wm = w >> 1, wn = w & 1;
    int m0 = blockIdx.x * 128, n0 = blockIdx.y * 128;

    f32x4 acc[4][4];
#pragma unroll
    for (int i = 0; i < 4; i++)
#pragma unroll
        for (int j = 0; j < 4; j++) acc[i][j] = (f32x4)(0.0f);

    for (int kt = 0; kt < 4096; kt += 64) {
        __syncthreads();
#pragma unroll
        for (int i = 0; i < 2; i++) {
            int c = i * 256 + tid;
            int r = c >> 2, seg = c & 3;
            *(uint4*)&A_lds[r * 72 + seg * 16] =
                *(const uint4*)&A[(size_t)(m0 + r) * 4096 + kt + seg * 16];
            *(uint4*)&B_lds[r * 72 + seg * 16] =
                *(const uint4*)&Bt[(size_t)(n0 + r) * 4096 + kt + seg * 16];
        }
        __syncthreads();
#pragma unroll
        for (int ks = 0; ks < 2; ks++) {
            long af[4], bf[4];
#pragma unroll
            for (int mt = 0; mt < 4; mt++)
                af[mt] = *(const long*)&A_lds[(wm * 64 + mt * 16 + l15) * 72 + ks * 32 + quad * 8];
#pragma unroll
            for (int nt = 0; nt < 4; nt++)
                bf[nt] = *(const long*)&B_lds[(wn * 64 + nt * 16 + l15) * 72 + ks * 32 + quad * 8];
#pragma unroll
            for (int mt = 0; mt < 4; mt++)
#pragma unroll
                for (int nt = 0; nt < 4; nt++)
                    acc[mt][nt] = __builtin_amdgcn_mfma_f32_16x16x32_fp8_fp8(af[mt], bf[nt], acc[mt][nt], 0, 0, 0);
        }
    }

#pragma unroll
    for (int mt = 0; mt < 4; mt++) {
#pragma unroll
        for (int r = 0; r < 4; r++) {
            int lr = m0 + wm * 64 + mt * 16 + quad * 4 + r;
            int gr = bh0 * 1024 + lr;
            float inv = 1.0f / denom[lr];
            int b = gr >> 13, h = (gr >> 10) & 7, n = gr & 1023;
            size_t base = ((size_t)(b * 1024 + n)) * 4096 + h * 512;
#pragma unroll
            for (int nt = 0; nt < 4; nt++) {
                int col = n0 + wn * 64 + nt * 16 + l15;
                float o = acc[mt][nt][r] * inv;
                float onb = __shfl_xor(o, 1);
                u16 blo = f2bf((l15 & 1) ? onb : o);
                u16 bhi = f2bf((l15 & 1) ? o : onb);
                u32 dw = (u32)blo | ((u32)bhi << 16);
                if (!(l15 & 1)) *(u32*)&rv[base + col] = dw;
            }
        }
    }
}

// ---------------------------------------------------------------------------
// sims v3: MFMA GEMM with split-bf16 precision (plain bf16 would misrank).
// sims[wi][m] ~ wh.mh + wh.ml + wl.mh. grid=(32,8). Epilogue: per-row argmax
// keys (ties -> smaller m), atomicMax into amax.
__global__ __launch_bounds__(256, 2) void sims_mfma_kernel(const u16* __restrict__ Ah,
                                                           const u16* __restrict__ Al,
                                                           const u16* __restrict__ Bh,
                                                           const u16* __restrict__ Bl,
                                                           u64* __restrict__ amax) {
    __shared__ __align__(16) u16 Ah_lds[128 * 40];
    __shared__ __align__(16) u16 Al_lds[128 * 40];
    __shared__ __align__(16) u16 Bh_lds[128 * 40];
    __shared__ __align__(16) u16 Bl_lds[128 * 40];
    int tid = threadIdx.x;
    int w = tid >> 6, lane = tid & 63, l15 = lane & 15, quad = lane >> 4;
    int wm = w >> 1, wn = w & 1;
    int n0 = blockIdx.x * 128, m0 = blockIdx.y * 128;

    f32x4 acc[4][4];
#pragma unroll
    for (int i = 0; i < 4; i++)
#pragma unroll
        for (int j = 0; j < 4; j++) acc[i][j] = (f32x4)(0.0f);

    for (int kt = 0; kt < 512; kt += 32) {
        __syncthreads();
#pragma unroll
        for (int i = 0; i < 2; i++) {
            int c = i * 256 + tid;
            int r = c >> 2, col = c & 3;
            size_t ga = (size_t)(m0 + r) * 512 + kt + col * 8;
            size_t gb = (size_t)(n0 + r) * 512 + kt + col * 8;
            *(uint4*)&Ah_lds[r * 40 + col * 8] = *(const uint4*)&Ah[ga];
            *(uint4*)&Al_lds[r * 40 + col * 8] = *(const uint4*)&Al[ga];
            *(uint4*)&Bh_lds[r * 40 + col * 8] = *(const uint4*)&Bh[gb];
            *(uint4*)&Bl_lds[r * 40 + col * 8] = *(const uint4*)&Bl[gb];
        }
        __syncthreads();
        short8 afh[4], afl[4], bfh[4], bfl[4];
#pragma unroll
        for (int mt = 0; mt < 4; mt++) {
            int off = (wm * 64 + mt * 16 + l15) * 40 + quad * 8;
            afh[mt] = *(const short8*)&Ah_lds[off];
            afl[mt] = *(const short8*)&Al_lds[off];
        }
#pragma unroll
        for (int nt = 0; nt < 4; nt++) {
            int off = (wn * 64 + nt * 16 + l15) * 40 + quad * 8;
            bfh[nt] = *(const short8*)&Bh_lds[off];
            bfl[nt] = *(const short8*)&Bl_lds[off];
        }
#pragma unroll
        for (int mt = 0; mt < 4; mt++)
#pragma unroll
            for (int nt = 0; nt < 4; nt++) {
                acc[mt][nt] = __builtin_amdgcn_mfma_f32_16x16x32_bf16(afh[mt], bfh[nt], acc[mt][nt], 0, 0, 0);
                acc[mt][nt] = __builtin_amdgcn_mfma_f32_16x16x32_bf16(afh[mt], bfl[nt], acc[mt][nt], 0, 0, 0);
                acc[mt][nt] = __builtin_amdgcn_mfma_f32_16x16x32_bf16(afl[mt], bfh[nt], acc[mt][nt], 0, 0, 0);
            }
    }

#pragma unroll
    for (int mt = 0; mt < 4; mt++) {
#pragma unroll
        for (int r = 0; r < 4; r++) {
            int row = m0 + wm * 64 + mt * 16 + quad * 4 + r;  // wi index
            u64 best = 0;
#pragma unroll
            for (int nt = 0; nt < 4; nt++) {
                int col = n0 + wn * 64 + nt * 16 + l15;       // slot index
                u32 bb = __float_as_uint(acc[mt][nt][r]);
                bb = (bb & 0x80000000u) ? ~bb : (bb | 0x80000000u);
                u64 key = ((u64)bb << 32) | (u32)(4095 - col);
                best = best > key ? best : key;
            }
            u64 o;
            o = __shfl_xor(best, 1); best = best > o ? best : o;
            o = __shfl_xor(best, 2); best = best > o ? best : o;
            o = __shfl_xor(best, 4); best = best > o ? best : o;
            o = __shfl_xor(best, 8); best = best > o ? best : o;
            if (l15 == 0) atomicMax(&amax[row], best);
        }
    }
}

// ---------------------------------------------------------------------------
// chains_build v2: decode idx, build per-slot chains. 16 blocks x 64 threads;
// scans over an LDS mirror of all 1024 decoded indices.
__global__ __launch_bounds__(64) void chains_build_kernel(const u64* __restrict__ amax,
                                                          int* __restrict__ idx,
                                                          int* __restrict__ nxt,
                                                          int* __restrict__ heads,
                                                          int* __restrict__ count) {
    __shared__ int sidx[1024];
    int tid = threadIdx.x;
    for (int j = tid; j < 1024; j += 64)
        sidx[j] = 4095 - (int)(u32)(amax[j] & 0xFFFFFFFFull);
    __syncthreads();
    int i = blockIdx.x * 64 + tid;
    int my = sidx[i];
    idx[i] = my;
    int nx = -1;
    for (int j = i + 1; j < 1024; j++)
        if (sidx[j] == my) { nx = j; break; }
    nxt[i] = nx;
    bool head = true;
    for (int j = 0; j < i; j++)
        if (sidx[j] == my) { head = false; break; }
    if (head) {
        int p = atomicAdd(count, 1);
        heads[p] = i;
    }
}

// ---------------------------------------------------------------------------
// G1[i][j] = write_keys[i] . Wg[0:512, j] + bg[j]   (fp32). 8 rows/block, grid=128.
__global__ __launch_bounds__(256) void g1_gemm_kernel(const float* __restrict__ wk,
                                                      const float* __restrict__ Wg,
                                                      const float* __restrict__ bg,
                                                      float* __restrict__ G1) {
    __shared__ float wkl[8][512];
    int tid = threadIdx.x;
    int i0 = blockIdx.x * 8;
    for (int i = tid; i < 8 * 512; i += 256) wkl[i >> 9][i & 511] = wk[(size_t)i0 * 512 + i];
    __syncthreads();
    float a0[8], a1[8];
#pragma unroll
    for (int i = 0; i < 8; i++) { a0[i] = 0.f; a1[i] = 0.f; }
    for (int c = 0; c < 512; c++) {
        float w0 = Wg[(size_t)c * 512 + tid];
        float w1 = Wg[(size_t)c * 512 + tid + 256];
#pragma unroll
        for (int ii = 0; ii < 8; ii++) {
            float s = wkl[ii][c];
            a0[ii] += s * w0; a1[ii] += s * w1;
        }
    }
    float b0 = bg[tid], b1 = bg[tid + 256];
#pragma unroll
    for (int ii = 0; ii < 8; ii++) {
        G1[(size_t)(i0 + ii) * 512 + tid] = a0[ii] + b0;
        G1[(size_t)(i0 + ii) * 512 + tid + 256] = a1[ii] + b1;
    }
}

// ---------------------------------------------------------------------------
// Apply per-slot chains sequentially (fp32). block = 256 threads per chain.
__global__ __launch_bounds__(256) void chain_apply_kernel(const int* __restrict__ heads,
                                                          const int* __restrict__ count,
                                                          const int* __restrict__ idx,
                                                          const int* __restrict__ nxt,
                                                          const float* __restrict__ G1,
                                                          const float* __restrict__ Wg,
                                                          const float* __restrict__ wk,
                                                          const float* __restrict__ wv,
                                                          const float* __restrict__ mk,
                                                          const float* __restrict__ mv,
                                                          float* __restrict__ outK,
                                                          float* __restrict__ outV) {
    int b = blockIdx.x;
    if (b >= *count) return;
    int i = heads[b];
    int s = idx[i];
    int tid = threadIdx.x;
    __shared__ float V[512];
    V[tid] = mv[(size_t)s * 512 + tid];
    V[tid + 256] = mv[(size_t)s * 512 + tid + 256];
    float k0 = mk[(size_t)s * 512 + tid], k1 = mk[(size_t)s * 512 + tid + 256];
    __syncthreads();
    while (i >= 0) {
        float a0 = G1[(size_t)i * 512 + tid], a1 = G1[(size_t)i * 512 + tid + 256];
        for (int c = 0; c < 512; c++) {
            float vc = V[c];
            a0 += vc * Wg[(size_t)(512 + c) * 512 + tid];
            a1 += vc * Wg[(size_t)(512 + c) * 512 + tid + 256];
        }
        float g0 = 1.f / (1.f + __expf(-a0));
        float g1 = 1.f / (1.f + __expf(-a1));
        __syncthreads(); // everyone finished reading V
        k0 = g0 * wk[(size_t)i * 512 + tid] + (1.f - g0) * k0;
        k1 = g1 * wk[(size_t)i * 512 + tid + 256] + (1.f - g1) * k1;
        V[tid] = g0 * wv[(size_t)i * 512 + tid] + (1.f - g0) * V[tid];
        V[tid + 256] = g1 * wv[(size_t)i * 512 + tid + 256] + (1.f - g1) * V[tid + 256];
        __syncthreads();
        i = nxt[i];
    }
    outK[(size_t)s * 512 + tid] = k0;
    outK[(size_t)s * 512 + tid + 256] = k1;
    outV[(size_t)s * 512 + tid] = V[tid];
    outV[(size_t)s * 512 + tid + 256] = V[tid + 256];
}

// ---------------------------------------------------------------------------
extern "C" void kernel_launch(void* const* d_in, const int* in_sizes, int n_in,
                              void* d_out, int out_size, void* d_ws, size_t ws_size,
                              hipStream_t stream) {
    const float* queries = (const float*)d_in[0]; // [4,1024,512]
    const float* wkeys   = (const float*)d_in[1]; // [1024,512]
    const float* wvals   = (const float*)d_in[2]; // [1024,512]
    const float* mkeys   = (const float*)d_in[3]; // [4096,512]
    const float* mvals   = (const float*)d_in[4]; // [4096,512]
    const float* Wq      = (const float*)d_in[5]; // [512,4096]
    const float* bq      = (const float*)d_in[6]; // [4096]
    const float* Wvp     = (const float*)d_in[7]; // [4096,512]
    const float* bvp     = (const float*)d_in[8]; // [512]
    const float* Wg      = (const float*)d_in[9]; // [1024,512]
    const float* bg      = (const float*)d_in[10];// [512]

    float* out_read = (float*)d_out;              // [4,1024,512]
    float* out_k = out_read + (size_t)4 * 1024 * 512; // [4096,512]
    float* out_v = out_k + (size_t)4096 * 512;        // [4096,512]

    char* ws = (char*)d_ws;
    const size_t MB = 1024 * 1024;
    // region [0, 4MB): Qbf during prep/q-proj, then reused for meta + denom
    u16* Qbf  = (u16*)(ws);            // 4 MB   queries bf16 [4096,512]
    u16* WqT  = (u16*)(ws + 4 * MB);   // 4 MB   Wq^T bf16 [4096,512]
    u16* Qatt = (u16*)(ws + 8 * MB);   // 32 MB  q bf16 [(b,h),n,d] = [32768,512]
    u16* Kb   = (u16*)(ws + 40 * MB);  // 4 MB   mem_keys bf16 [4096,512]
    u8*  Vt8  = (u8*)(ws + 44 * MB);   // 2 MB   mem_values^T fp8 [512,4096]
    u16* rv   = (u16*)(ws + 48 * MB);  // 32 MB  attention out bf16 [4096,4096]
    u16* WvpT = (u16*)(ws + 80 * MB);  // 4 MB   Wvp^T bf16 [512,4096]
    // write-path buffers (dead before attention's P overlay):
    u16* mn_hi = (u16*)(ws + 84 * MB); // 4 MB  normalized keys hi bf16 [4096,512]
    u16* mn_lo = (u16*)(ws + 88 * MB); // 4 MB  normalized keys lo bf16 [4096,512]
    float* G1  = (float*)(ws + 92 * MB); // 2 MB gate pre from write_keys [1024,512]
    u16* wk_hi = (u16*)(ws + 94 * MB); // 1 MB  write_keys hi bf16 [1024,512]
    u16* wk_lo = (u16*)(ws + 95 * MB); // 1 MB  write_keys lo bf16 [1024,512]
    // meta + denom overlay the dead Qbf region (valid after q-proj completes)
    u64* amax   = (u64*)(ws);                   // 8 KB
    int* count  = (int*)(ws + 8192);            // 4 B
    int* idx    = (int*)(ws + 8192 + 256);      // 4 KB
    int* nxt    = (int*)(ws + 8192 + 256 + 4096);   // 4 KB
    int* heads  = (int*)(ws + 8192 + 256 + 8192);   // 4 KB
    float* denom = (float*)(ws + 32 * 1024);    // 128 KB [32768]
    // P (fp8) overlays the dead write-path region (valid after chain_apply)
    u8* P = (u8*)(ws + 84 * MB);                // up to 128 MB [G*1024, 4096]
    (void)in_sizes; (void)n_in; (void)out_size;

    // chunk size over bh: P needs G*4MB (fp8) starting at 84MB
    size_t avail = (ws_size > 84 * MB) ? ws_size - 84 * MB : 0;
    int G = 2; // proven-safe floor
    for (int g = 32; g >= 2; g >>= 1)
        if ((size_t)g * 4 * MB <= avail) { G = g; break; }

    // new_keys / new_values start as copies of mem_keys / mem_values
    hipMemcpyAsync(out_k, mkeys, (size_t)4096 * 512 * 4, hipMemcpyDeviceToDevice, stream);
    hipMemcpyAsync(out_v, mvals, (size_t)4096 * 512 * 4, hipMemcpyDeviceToDevice, stream);

    // ---- prep casts / transposes ----
    cast_bf16_kernel<<<2048, 256, 0, stream>>>(queries, Qbf);
    cast_transpose_kernel<<<dim3(4096 / 32, 512 / 32), 256, 0, stream>>>(Wq, WqT, 512, 4096);
    cast_transpose_kernel<<<dim3(512 / 32, 4096 / 32), 256, 0, stream>>>(Wvp, WvpT, 4096, 512);
    cast_transpose_fp8_kernel<<<dim3(512 / 32, 4096 / 32), 256, 0, stream>>>(mvals, Vt8, 4096, 512);
    key_prep_kernel<<<4096, 256, 0, stream>>>(mkeys, mn_hi, mn_lo, Kb);
    split_bf16_kernel<<<512, 256, 0, stream>>>(wkeys, wk_hi, wk_lo);

    // ---- q-proj (last user of Qbf/WqT) ----
    gemm_bt_kernel<128, 1><<<dim3(32, 32), 256, 0, stream>>>(Qbf, WqT, bq, (void*)Qatt, 4096, 4096, 512);

    // ---- write path (fp32-accurate), frees buffers for the P overlay after ----
    hipMemsetAsync(ws, 0, 8192 + 256, stream);          // amax + count (Qbf now dead)
    hipMemsetAsync(denom, 0, 32768 * 4, stream);        // denom
    sims_mfma_kernel<<<dim3(32, 8), 256, 0, stream>>>(wk_hi, wk_lo, mn_hi, mn_lo, amax);
    chains_build_kernel<<<16, 64, 0, stream>>>(amax, idx, nxt, heads, count);
    g1_gemm_kernel<<<128, 256, 0, stream>>>(wkeys, Wg, bg, G1);
    chain_apply_kernel<<<1024, 256, 0, stream>>>(heads, count, idx, nxt, G1, Wg,
                                                 wkeys, wvals, mkeys, mvals, out_k, out_v);

    // ---- attention as two GEMM passes (P in fp8), chunked over bh ----
    for (int bh0 = 0; bh0 < 32; bh0 += G) {
        const u16* Achunk = Qatt + (size_t)bh0 * 1024 * 512;
        float* dchunk = denom + bh0 * 1024;
        s_exp_gemm_kernel<<<dim3(32, G * 8), 256, 0, stream>>>(Achunk, Kb, P, dchunk);
        pv_gemm_kernel<<<dim3(G * 8, 4), 256, 0, stream>>>(P, Vt8, dchunk, rv, bh0);
    }

    // ---- out-proj ----
    gemm_bt_kernel<64, 0><<<dim3(8, 32), 256, 0, stream>>>(rv, WvpT, bvp, (void*)out_read, 4096, 512, 4096);
}